// Round 1
// baseline (785.298 us; speedup 1.0000x reference)
//
#include <hip/hip_runtime.h>
#include <hip/hip_bf16.h>
#include <cstdint>

// Problem constants: B=2, S=2048, D=2048, H=16, DH=128, past_length=0 (fixed).

typedef __attribute__((ext_vector_type(8))) __bf16 bf16x8;
typedef __attribute__((ext_vector_type(4))) float f32x4;
typedef __attribute__((ext_vector_type(4))) float floatv4;
typedef __attribute__((ext_vector_type(4))) unsigned short ushortv4;

#define LOG2E 1.4426950408889634f

__device__ __forceinline__ unsigned short f2bf(float f) {
    union { float f; unsigned u; } v; v.f = f;
    unsigned r = v.u + 0x7fffu + ((v.u >> 16) & 1u);
    return (unsigned short)(r >> 16);
}

// global -> LDS async copy, 16B per lane. LDS dest is wave-uniform base + lane*16.
// AS casts via integer round-trip (AS3 ptrs are 32-bit offsets; low 32 bits of a
// generic LDS pointer ARE the offset).
#define GLL16(g, l)                                                                   \
    __builtin_amdgcn_global_load_lds(                                                 \
        (const __attribute__((address_space(1))) void*)(uintptr_t)(g),                \
        (__attribute__((address_space(3))) void*)(unsigned)(uintptr_t)(l), 16, 0, 0)

// ---------------- cast kernels ----------------
__global__ __launch_bounds__(256) void cast_bf16_k(const float* __restrict__ src,
                                                   unsigned short* __restrict__ dst, int n4) {
    int i = blockIdx.x * 256 + threadIdx.x;
    if (i >= n4) return;
    floatv4 v = reinterpret_cast<const floatv4*>(src)[i];
    ushortv4 o;
    o.x = f2bf(v.x); o.y = f2bf(v.y); o.z = f2bf(v.z); o.w = f2bf(v.w);
    reinterpret_cast<ushortv4*>(dst)[i] = o;
}

// wkv (2048 x 256) f32 -> wkvT (256 x 2048) bf16
__global__ __launch_bounds__(256) void cast_t_wkv_k(const float* __restrict__ src,
                                                    unsigned short* __restrict__ dst) {
    int i = blockIdx.x * 256 + threadIdx.x;  // 0..524287
    int k = i >> 8, j = i & 255;
    dst[j * 2048 + k] = f2bf(src[i]);
}

// ---------------- BT GEMM: C[M][N] = A[M][K] * B[N][K]^T (bf16 in, f32 out) -------
// 128x128 tile, BK=32, 4 waves (2x2), each wave 64x64 via 4x4 16x16x32 MFMA frags.
__global__ __launch_bounds__(256) void gemm_bt(const unsigned short* __restrict__ A,
                                               const unsigned short* __restrict__ B,
                                               float* __restrict__ C,
                                               int M, int N, int K) {
    __shared__ __align__(16) unsigned short As[4096];  // [128][32]
    __shared__ __align__(16) unsigned short Bs[4096];
    const int tid  = threadIdx.x;
    const int lane = tid & 63;
    const int wid  = tid >> 6;
    const int wr   = wid >> 1;
    const int wc   = wid & 1;
    const size_t row0 = (size_t)blockIdx.y * 128;
    const size_t col0 = (size_t)blockIdx.x * 128;
    f32x4 acc[4][4];
#pragma unroll
    for (int m = 0; m < 4; ++m)
#pragma unroll
        for (int n = 0; n < 4; ++n) acc[m][n] = (f32x4){0.f, 0.f, 0.f, 0.f};

    // staging: thread tid covers rows tid/4 and tid/4+64, cols (tid%4)*8 .. +8
    const int srow = tid >> 2;
    const int scol = (tid & 3) << 3;
    const unsigned short* Ag = A + (row0 + srow) * (size_t)K + scol;
    const unsigned short* Bg = B + (col0 + srow) * (size_t)K + scol;
    unsigned short* AsW = &As[wid << 9];   // wave base: wid*512 elems = wid*1024 B
    unsigned short* BsW = &Bs[wid << 9];

    const int lrow = lane & 15;
    const int lk   = (lane >> 4) << 3;  // 0,8,16,24

    for (int k0 = 0; k0 < K; k0 += 32) {
        GLL16(Ag + k0, AsW);
        GLL16(Ag + k0 + (size_t)64 * K, AsW + 2048);
        GLL16(Bg + k0, BsW);
        GLL16(Bg + k0 + (size_t)64 * K, BsW + 2048);
        __syncthreads();  // emits vmcnt(0) before barrier -> LDS ready
        bf16x8 af[4], bfr[4];
#pragma unroll
        for (int m = 0; m < 4; ++m)
            af[m] = *reinterpret_cast<const bf16x8*>(&As[(wr * 64 + m * 16 + lrow) * 32 + lk]);
#pragma unroll
        for (int n = 0; n < 4; ++n)
            bfr[n] = *reinterpret_cast<const bf16x8*>(&Bs[(wc * 64 + n * 16 + lrow) * 32 + lk]);
#pragma unroll
        for (int m = 0; m < 4; ++m)
#pragma unroll
            for (int n = 0; n < 4; ++n)
                acc[m][n] = __builtin_amdgcn_mfma_f32_16x16x32_bf16(af[m], bfr[n], acc[m][n], 0, 0, 0);
        __syncthreads();
    }
    // epilogue: D row = 4*(lane>>4)+reg, col = lane&15  (m89-verified)
    const size_t orow0 = row0 + wr * 64 + ((lane >> 4) << 2);
    const size_t ocol  = col0 + wc * 64 + lrow;
#pragma unroll
    for (int m = 0; m < 4; ++m)
#pragma unroll
        for (int n = 0; n < 4; ++n)
#pragma unroll
            for (int r = 0; r < 4; ++r)
                C[(orow0 + m * 16 + r) * (size_t)N + ocol + n * 16] = acc[m][n][r];
}

// ---------------- RoPE + pack ----------------
// Qf (4096 x 2048 f32), KVf (4096 x 256 f32) ->
//   Qb  [b][h][s][128] bf16 (roped)
//   Kb  [b][s][128]    bf16 (roped)
//   Vt  [b][128][s]    bf16 (V transposed)
//   Kout/Vout fp32 (un-roped) -> d_out
__global__ __launch_bounds__(256) void rope_pack_k(const float* __restrict__ Qf,
                                                   const float* __restrict__ KVf,
                                                   unsigned short* __restrict__ Qb,
                                                   unsigned short* __restrict__ Kb,
                                                   unsigned short* __restrict__ Vt,
                                                   float* __restrict__ Kout,
                                                   float* __restrict__ Vout) {
    const int row = blockIdx.x;      // b*2048 + s
    const int b = row >> 11;
    const int s = row & 2047;
    const int t = threadIdx.x;
    const float* qrow = Qf + (size_t)row * 2048;
#pragma unroll
    for (int it = 0; it < 4; ++it) {
        int p = t + it * 256;        // pair index 0..1023
        int h = p >> 6;
        int i = p & 63;
        float fr  = exp2f(-(float)i * 0.20762050593045858f);  // 10000^(-i/64)
        float ang = (float)s * fr;
        float sn, c;
        sincosf(ang, &sn, &c);
        float x1 = qrow[h * 128 + i];
        float x2 = qrow[h * 128 + i + 64];
        size_t qb = (((size_t)(b * 16 + h)) * 2048 + s) * 128;
        Qb[qb + i]      = f2bf(x1 * c - x2 * sn);
        Qb[qb + i + 64] = f2bf(x2 * c + x1 * sn);
    }
    const float* kvrow = KVf + (size_t)row * 256;
    if (t < 128) {
        float kv = kvrow[t];
        float vv = kvrow[128 + t];
        Kout[(size_t)row * 128 + t] = kv;   // un-roped K output
        Vout[(size_t)row * 128 + t] = vv;
        Vt[((size_t)(b * 128 + t)) * 2048 + s] = f2bf(vv);
    }
    if (t < 64) {
        float fr  = exp2f(-(float)t * 0.20762050593045858f);
        float ang = (float)s * fr;
        float sn, c;
        sincosf(ang, &sn, &c);
        float x1 = kvrow[t];
        float x2 = kvrow[t + 64];
        size_t ko = ((size_t)b * 2048 + s) * 128;
        Kb[ko + t]      = f2bf(x1 * c - x2 * sn);
        Kb[ko + t + 64] = f2bf(x2 * c + x1 * sn);
    }
}

// ---------------- causal flash attention (MQA) ----------------
// block = (qblk, h, b); 4 waves x 16 q-rows; 64-key tiles; K/V from global (L2).
__global__ __launch_bounds__(256) void attn_k(const unsigned short* __restrict__ Qb,
                                              const unsigned short* __restrict__ Kb,
                                              const unsigned short* __restrict__ Vt,
                                              unsigned short* __restrict__ Ob) {
    const int qblk = blockIdx.x;
    const int h = blockIdx.y;
    const int b = blockIdx.z;
    const int tid = threadIdx.x;
    const int lane = tid & 63;
    const int w = tid >> 6;
    __shared__ __align__(16) unsigned short Plds[4][16][72];  // padded 64->72
    const int lrow = lane & 15;
    const int lk   = (lane >> 4) << 3;
    const int qrl  = (lane >> 4) << 2;     // local output-row base
    const int q0 = qblk * 64 + w * 16;     // this wave's first q row

    const unsigned short* qbase = Qb + (((size_t)(b * 16 + h)) * 2048 + q0 + lrow) * 128;
    bf16x8 qf[4];
#pragma unroll
    for (int kc = 0; kc < 4; ++kc)
        qf[kc] = *reinterpret_cast<const bf16x8*>(qbase + kc * 32 + lk);

    f32x4 O[8];
#pragma unroll
    for (int nb = 0; nb < 8; ++nb) O[nb] = (f32x4){0.f, 0.f, 0.f, 0.f};
    float mr[4] = {-1e30f, -1e30f, -1e30f, -1e30f};
    float lr[4] = {0.f, 0.f, 0.f, 0.f};

    const unsigned short* kbB = Kb + (size_t)b * 2048 * 128;
    const unsigned short* vtB = Vt + (size_t)b * 128 * 2048;
    const float scale = 0.08838834764831845f;  // 1/sqrt(128)

    for (int kt = 0; kt <= qblk; ++kt) {
        // --- scores: S = q * K^T   (16 x 64) ---
        f32x4 sc[4];
#pragma unroll
        for (int n = 0; n < 4; ++n) {
            f32x4 s = (f32x4){0.f, 0.f, 0.f, 0.f};
            const unsigned short* kp = kbB + ((size_t)(kt * 64 + n * 16 + lrow)) * 128 + lk;
#pragma unroll
            for (int kc = 0; kc < 4; ++kc) {
                bf16x8 kf = *reinterpret_cast<const bf16x8*>(kp + kc * 32);
                s = __builtin_amdgcn_mfma_f32_16x16x32_bf16(qf[kc], kf, s, 0, 0, 0);
            }
            sc[n] = s;
        }
        const bool last = (kt == qblk);
        // --- scale + causal mask + row max (16-lane groups) ---
        float tm[4];
#pragma unroll
        for (int r = 0; r < 4; ++r) {
            int qg = q0 + qrl + r;
#pragma unroll
            for (int n = 0; n < 4; ++n) {
                float sv = sc[n][r] * scale;
                if (last && (kt * 64 + n * 16 + lrow > qg)) sv = -1e30f;
                sc[n][r] = sv;
            }
            tm[r] = fmaxf(fmaxf(sc[0][r], sc[1][r]), fmaxf(sc[2][r], sc[3][r]));
#pragma unroll
            for (int o = 1; o < 16; o <<= 1)
                tm[r] = fmaxf(tm[r], __shfl_xor(tm[r], o));
        }
        // --- online softmax ---
        float corr[4];
#pragma unroll
        for (int r = 0; r < 4; ++r) {
            float mn = fmaxf(mr[r], tm[r]);
            corr[r] = exp2f((mr[r] - mn) * LOG2E);
            mr[r] = mn;
            float sum = 0.f;
#pragma unroll
            for (int n = 0; n < 4; ++n) {
                float pv = exp2f((sc[n][r] - mn) * LOG2E);
                sc[n][r] = pv;
                sum += pv;
            }
#pragma unroll
            for (int o = 1; o < 16; o <<= 1)
                sum += __shfl_xor(sum, o);
            lr[r] = lr[r] * corr[r] + sum;
        }
#pragma unroll
        for (int nb = 0; nb < 8; ++nb)
#pragma unroll
            for (int r = 0; r < 4; ++r)
                O[nb][r] *= corr[r];
        // --- P (C-layout) -> LDS -> A-layout frags ---
#pragma unroll
        for (int n = 0; n < 4; ++n)
#pragma unroll
            for (int r = 0; r < 4; ++r)
                Plds[w][qrl + r][n * 16 + lrow] = f2bf(sc[n][r]);
        __syncthreads();
        bf16x8 pa[2];
#pragma unroll
        for (int kc2 = 0; kc2 < 2; ++kc2)
            pa[kc2] = *reinterpret_cast<const bf16x8*>(&Plds[w][lrow][kc2 * 32 + lk]);
        // --- O += P * V   via Vt (B-frag = contiguous 8 keys at fixed d) ---
#pragma unroll
        for (int nb = 0; nb < 8; ++nb) {
            const unsigned short* vp = vtB + ((size_t)(nb * 16 + lrow)) * 2048 + kt * 64 + lk;
#pragma unroll
            for (int kc2 = 0; kc2 < 2; ++kc2) {
                bf16x8 vf = *reinterpret_cast<const bf16x8*>(vp + kc2 * 32);
                O[nb] = __builtin_amdgcn_mfma_f32_16x16x32_bf16(pa[kc2], vf, O[nb], 0, 0, 0);
            }
        }
        __syncthreads();  // protect Plds before next tile overwrites
    }
    float inv[4];
#pragma unroll
    for (int r = 0; r < 4; ++r) inv[r] = 1.0f / lr[r];
#pragma unroll
    for (int nb = 0; nb < 8; ++nb)
#pragma unroll
        for (int r = 0; r < 4; ++r)
            Ob[((size_t)(b * 2048 + q0 + qrl + r)) * 2048 + h * 128 + nb * 16 + lrow] =
                f2bf(O[nb][r] * inv[r]);
}

// ---------------- launch ----------------
extern "C" void kernel_launch(void* const* d_in, const int* in_sizes, int n_in,
                              void* d_out, int out_size, void* d_ws, size_t ws_size,
                              hipStream_t stream) {
    const float* x   = (const float*)d_in[0];
    const float* wq  = (const float*)d_in[1];
    const float* wkv = (const float*)d_in[2];
    const float* wo  = (const float*)d_in[3];
    // d_in[4] = past_length, fixed 0 in this problem.

    float* out  = (float*)d_out;                 // (B,S,D) = 8388608
    float* Kout = out + 8388608;                 // (B,S,DH) = 524288
    float* Vout = Kout + 524288;

    char* ws = (char*)d_ws;
    // lifetime-aliased workspace plan (peak ~69 MB)
    unsigned short* xb   = (unsigned short*)(ws + 0);          // 16 MB [casts -> gemms]
    unsigned short* wqb  = (unsigned short*)(ws + 16777216);   //  8 MB [-> gemm Q]
    unsigned short* wkvT = (unsigned short*)(ws + 25165824);   //  1 MB [-> gemm KV]
    unsigned short* wob  = (unsigned short*)(ws + 26214400);   //  8 MB [-> final gemm]
    float*          KVf  = (float*)(ws + 34603008);            //  4 MB [gemm KV -> rope]
    float*          Qf   = (float*)(ws + 38797312);            // 32 MB [gemm Q -> rope]
    unsigned short* Qb   = (unsigned short*)(ws + 0);          // 16 MB (aliases dead xb)
    unsigned short* Kb   = (unsigned short*)(ws + 16777216);   //  1 MB (aliases dead wqb)
    unsigned short* Vt   = (unsigned short*)(ws + 17825792);   //  1 MB (aliases dead wqb)
    unsigned short* Ob   = (unsigned short*)(ws + 34603008);   // 16 MB (aliases dead KVf/Qf)

    cast_bf16_k<<<8192, 256, 0, stream>>>(x,  xb,  2097152);
    cast_bf16_k<<<4096, 256, 0, stream>>>(wq, wqb, 1048576);
    cast_bf16_k<<<4096, 256, 0, stream>>>(wo, wob, 1048576);
    cast_t_wkv_k<<<2048, 256, 0, stream>>>(wkv, wkvT);

    gemm_bt<<<dim3(2, 32),  256, 0, stream>>>(xb, wkvT, KVf, 4096, 256,  2048);
    gemm_bt<<<dim3(16, 32), 256, 0, stream>>>(xb, wqb,  Qf,  4096, 2048, 2048);

    rope_pack_k<<<4096, 256, 0, stream>>>(Qf, KVf, Qb, Kb, Vt, Kout, Vout);

    attn_k<<<dim3(32, 16, 2), 256, 0, stream>>>(Qb, Kb, Vt, Ob);

    gemm_bt<<<dim3(16, 32), 256, 0, stream>>>(Ob, wob, out, 4096, 2048, 2048);
}

// Round 2
// 479.975 us; speedup vs baseline: 1.6361x; 1.6361x over previous
//
#include <hip/hip_runtime.h>
#include <hip/hip_bf16.h>
#include <cstdint>

// Problem constants: B=2, S=2048, D=2048, H=16, DH=128, past_length=0 (fixed).

typedef __attribute__((ext_vector_type(8))) __bf16 bf16x8;
typedef __attribute__((ext_vector_type(4))) float f32x4;
typedef __attribute__((ext_vector_type(16))) float f32x16;
typedef __attribute__((ext_vector_type(4))) float floatv4;
typedef __attribute__((ext_vector_type(4))) unsigned short ushortv4;
typedef __attribute__((ext_vector_type(4))) unsigned int uintv4;

#define LOG2E 1.4426950408889634f

__device__ __forceinline__ unsigned short f2bf(float f) {
    union { float f; unsigned u; } v; v.f = f;
    unsigned r = v.u + 0x7fffu + ((v.u >> 16) & 1u);
    return (unsigned short)(r >> 16);
}

__device__ __forceinline__ unsigned pk2(float a, float b) {
    return (unsigned)f2bf(a) | ((unsigned)f2bf(b) << 16);
}

__device__ __forceinline__ f32x16 zero16() {
    f32x16 z;
#pragma unroll
    for (int i = 0; i < 16; ++i) z[i] = 0.f;
    return z;
}

// global -> LDS async copy, 16B per lane.
#define GLL16(g, l)                                                                   \
    __builtin_amdgcn_global_load_lds(                                                 \
        (const __attribute__((address_space(1))) void*)(uintptr_t)(g),                \
        (__attribute__((address_space(3))) void*)(unsigned)(uintptr_t)(l), 16, 0, 0)

// ---------------- cast kernels ----------------
__global__ __launch_bounds__(256) void cast_bf16_k(const float* __restrict__ src,
                                                   unsigned short* __restrict__ dst, int n4) {
    int i = blockIdx.x * 256 + threadIdx.x;
    if (i >= n4) return;
    floatv4 v = reinterpret_cast<const floatv4*>(src)[i];
    ushortv4 o;
    o.x = f2bf(v.x); o.y = f2bf(v.y); o.z = f2bf(v.z); o.w = f2bf(v.w);
    reinterpret_cast<ushortv4*>(dst)[i] = o;
}

// wkv (2048 x 256) f32 -> wkvT (256 x 2048) bf16
__global__ __launch_bounds__(256) void cast_t_wkv_k(const float* __restrict__ src,
                                                    unsigned short* __restrict__ dst) {
    int i = blockIdx.x * 256 + threadIdx.x;  // 0..524287
    int k = i >> 8, j = i & 255;
    dst[j * 2048 + k] = f2bf(src[i]);
}

// ---------------- BT GEMM: C[M][N] = A[M][K] * B[N][K]^T (bf16 in, f32 out) -------
__global__ __launch_bounds__(256) void gemm_bt(const unsigned short* __restrict__ A,
                                               const unsigned short* __restrict__ B,
                                               float* __restrict__ C,
                                               int M, int N, int K) {
    __shared__ __align__(16) unsigned short As[4096];  // [128][32]
    __shared__ __align__(16) unsigned short Bs[4096];
    const int tid  = threadIdx.x;
    const int lane = tid & 63;
    const int wid  = tid >> 6;
    const int wr   = wid >> 1;
    const int wc   = wid & 1;
    const size_t row0 = (size_t)blockIdx.y * 128;
    const size_t col0 = (size_t)blockIdx.x * 128;
    f32x4 acc[4][4];
#pragma unroll
    for (int m = 0; m < 4; ++m)
#pragma unroll
        for (int n = 0; n < 4; ++n) acc[m][n] = (f32x4){0.f, 0.f, 0.f, 0.f};

    const int srow = tid >> 2;
    const int scol = (tid & 3) << 3;
    const unsigned short* Ag = A + (row0 + srow) * (size_t)K + scol;
    const unsigned short* Bg = B + (col0 + srow) * (size_t)K + scol;
    unsigned short* AsW = &As[wid << 9];
    unsigned short* BsW = &Bs[wid << 9];

    const int lrow = lane & 15;
    const int lk   = (lane >> 4) << 3;

    for (int k0 = 0; k0 < K; k0 += 32) {
        GLL16(Ag + k0, AsW);
        GLL16(Ag + k0 + (size_t)64 * K, AsW + 2048);
        GLL16(Bg + k0, BsW);
        GLL16(Bg + k0 + (size_t)64 * K, BsW + 2048);
        __syncthreads();
        bf16x8 af[4], bfr[4];
#pragma unroll
        for (int m = 0; m < 4; ++m)
            af[m] = *reinterpret_cast<const bf16x8*>(&As[(wr * 64 + m * 16 + lrow) * 32 + lk]);
#pragma unroll
        for (int n = 0; n < 4; ++n)
            bfr[n] = *reinterpret_cast<const bf16x8*>(&Bs[(wc * 64 + n * 16 + lrow) * 32 + lk]);
#pragma unroll
        for (int m = 0; m < 4; ++m)
#pragma unroll
            for (int n = 0; n < 4; ++n)
                acc[m][n] = __builtin_amdgcn_mfma_f32_16x16x32_bf16(af[m], bfr[n], acc[m][n], 0, 0, 0);
        __syncthreads();
    }
    const size_t orow0 = row0 + wr * 64 + ((lane >> 4) << 2);
    const size_t ocol  = col0 + wc * 64 + lrow;
#pragma unroll
    for (int m = 0; m < 4; ++m)
#pragma unroll
        for (int n = 0; n < 4; ++n)
#pragma unroll
            for (int r = 0; r < 4; ++r)
                C[(orow0 + m * 16 + r) * (size_t)N + ocol + n * 16] = acc[m][n][r];
}

// ---------------- RoPE + pack ----------------
__global__ __launch_bounds__(256) void rope_pack_k(const float* __restrict__ Qf,
                                                   const float* __restrict__ KVf,
                                                   unsigned short* __restrict__ Qb,
                                                   unsigned short* __restrict__ Kb,
                                                   unsigned short* __restrict__ Vt,
                                                   float* __restrict__ Kout,
                                                   float* __restrict__ Vout) {
    const int row = blockIdx.x;      // b*2048 + s
    const int b = row >> 11;
    const int s = row & 2047;
    const int t = threadIdx.x;
    const float* qrow = Qf + (size_t)row * 2048;
#pragma unroll
    for (int it = 0; it < 4; ++it) {
        int p = t + it * 256;        // pair index 0..1023
        int h = p >> 6;
        int i = p & 63;
        float fr  = exp2f(-(float)i * 0.20762050593045858f);  // 10000^(-i/64)
        float ang = (float)s * fr;
        float sn, c;
        sincosf(ang, &sn, &c);
        float x1 = qrow[h * 128 + i];
        float x2 = qrow[h * 128 + i + 64];
        size_t qb = (((size_t)(b * 16 + h)) * 2048 + s) * 128;
        Qb[qb + i]      = f2bf(x1 * c - x2 * sn);
        Qb[qb + i + 64] = f2bf(x2 * c + x1 * sn);
    }
    const float* kvrow = KVf + (size_t)row * 256;
    if (t < 128) {
        float kv = kvrow[t];
        float vv = kvrow[128 + t];
        Kout[(size_t)row * 128 + t] = kv;
        Vout[(size_t)row * 128 + t] = vv;
        Vt[((size_t)(b * 128 + t)) * 2048 + s] = f2bf(vv);
    }
    if (t < 64) {
        float fr  = exp2f(-(float)t * 0.20762050593045858f);
        float ang = (float)s * fr;
        float sn, c;
        sincosf(ang, &sn, &c);
        float x1 = kvrow[t];
        float x2 = kvrow[t + 64];
        size_t ko = ((size_t)b * 2048 + s) * 128;
        Kb[ko + t]      = f2bf(x1 * c - x2 * sn);
        Kb[ko + t + 64] = f2bf(x2 * c + x1 * sn);
    }
}

// ---------------- causal flash attention (MQA), wave-independent ----------------
// Each wave owns one 32-row q-tile; swapped QK^T (S^T = K·Q^T) so q = lane&31 and
// softmax is in-register (tree + one shfl_xor(32)); PV computed transposed
// (O^T = V^T·P^T) so O keeps q = lane&31 (scalar rescale). No LDS, no barriers.
// Work balance: b=0 waves take tile tb, b=1 waves take 63-tb; co-resident block
// pairs (i, i+256) then carry complementary (constant-sum) workloads.
__global__ __launch_bounds__(256, 2) void attn_k(const unsigned short* __restrict__ Qb,
                                                 const unsigned short* __restrict__ Kb,
                                                 const unsigned short* __restrict__ Vt,
                                                 unsigned short* __restrict__ Ob) {
    const int h = blockIdx.y, b = blockIdx.z;
    const int lane = threadIdx.x & 63;
    const int w = threadIdx.x >> 6;
    const int tb = blockIdx.x * 4 + w;       // 0..63
    const int t = b ? (63 - tb) : tb;        // complementary balance across batches
    const int q0 = t * 32;
    const int lq = lane & 31;                // q column (C/D col = lane&31)
    const int hl = lane >> 5;                // lane half
    const int kofs = hl * 8;                 // k-dim offset inside a 16-chunk

    // Q B-fragment (held): B[col=q][k] -> Qb[(b,h,q0+lq)][16c + kofs .. +8]
    const unsigned short* qp = Qb + (((size_t)(b * 16 + h)) * 2048 + q0 + lq) * 128 + kofs;
    bf16x8 qf[8];
#pragma unroll
    for (int c = 0; c < 8; ++c)
        qf[c] = *reinterpret_cast<const bf16x8*>(qp + 16 * c);

    f32x16 O[4];
#pragma unroll
    for (int dt = 0; dt < 4; ++dt) O[dt] = zero16();
    float m = -1e30f, l = 0.f;

    const int nkt = t / 2 + 1;               // number of 64-key tiles
    const unsigned short* kb = Kb + (size_t)b * 2048 * 128;
    const unsigned short* vb = Vt + (size_t)b * 128 * 2048;
    const float csc = 0.12751782377892224f;  // (1/sqrt(128)) * log2(e)

    for (int kt = 0; kt < nkt; ++kt) {
        // --- S^T = K · Q^T  (two 32-key sub-tiles) ---
        f32x16 S0 = zero16(), S1 = zero16();
        const unsigned short* kp0 = kb + ((size_t)(64 * kt + lq)) * 128 + kofs;
        const unsigned short* kp1 = kp0 + 32 * 128;
#pragma unroll
        for (int c = 0; c < 8; ++c) {
            bf16x8 k0 = *reinterpret_cast<const bf16x8*>(kp0 + 16 * c);
            bf16x8 k1 = *reinterpret_cast<const bf16x8*>(kp1 + 16 * c);
            S0 = __builtin_amdgcn_mfma_f32_32x32x16_bf16(k0, qf[c], S0, 0, 0, 0);
            S1 = __builtin_amdgcn_mfma_f32_32x32x16_bf16(k1, qf[c], S1, 0, 0, 0);
        }
        // --- scale (+ causal mask on last tile); log2-domain softmax ---
        float sc[32];
        const bool lastt = (kt == nkt - 1);
#pragma unroll
        for (int s = 0; s < 2; ++s)
#pragma unroll
            for (int r = 0; r < 16; ++r) {
                float v = (s ? S1[r] : S0[r]) * csc;
                if (lastt) {
                    int key = 64 * kt + 32 * s + (r & 3) + 8 * (r >> 2) + 4 * hl;
                    if (key > q0 + lq) v = -3.0e38f;
                }
                sc[16 * s + r] = v;
            }
        // row max: in-register tree + one cross-half shfl
        float tm[16];
#pragma unroll
        for (int i = 0; i < 16; ++i) tm[i] = fmaxf(sc[i], sc[i + 16]);
#pragma unroll
        for (int st = 8; st > 0; st >>= 1)
#pragma unroll
            for (int i = 0; i < st; ++i) tm[i] = fmaxf(tm[i], tm[i + st]);
        float mt = fmaxf(tm[0], __shfl_xor(tm[0], 32));
        float mn = fmaxf(m, mt);
        float corr = __builtin_amdgcn_exp2f(m - mn);
        m = mn;
#pragma unroll
        for (int i = 0; i < 32; ++i) sc[i] = __builtin_amdgcn_exp2f(sc[i] - mn);
        float ts[16];
#pragma unroll
        for (int i = 0; i < 16; ++i) ts[i] = sc[i] + sc[i + 16];
#pragma unroll
        for (int st = 8; st > 0; st >>= 1)
#pragma unroll
            for (int i = 0; i < st; ++i) ts[i] += ts[i + st];
        float sum = ts[0] + __shfl_xor(ts[0], 32);
        l = l * corr + sum;
#pragma unroll
        for (int dt = 0; dt < 4; ++dt)
#pragma unroll
            for (int r = 0; r < 16; ++r) O[dt][r] *= corr;
        // --- pack P into PV B-fragments (keys reg-local -> k-contiguous) ---
        // P reg r (sub s): key = 32s + (r&3) + 8*(r>>2) + 4*hl. B-frag for 16-key
        // chunk kc needs keys 16kc + 8*hl + 0..7. Pairs packed to bf16 words, then
        // the half-swap permutation via shfl_xor(32) + select.
        unsigned pw[4][4];
#pragma unroll
        for (int s = 0; s < 2; ++s)
#pragma unroll
            for (int c2 = 0; c2 < 2; ++c2) {
                const int rb = 16 * s + 8 * c2;
                unsigned X0 = pk2(sc[rb + 0], sc[rb + 1]);
                unsigned X1 = pk2(sc[rb + 2], sc[rb + 3]);
                unsigned X2 = pk2(sc[rb + 4], sc[rb + 5]);
                unsigned X3 = pk2(sc[rb + 6], sc[rb + 7]);
                unsigned y0 = __shfl_xor(X0, 32);
                unsigned y1 = __shfl_xor(X1, 32);
                unsigned y2 = __shfl_xor(X2, 32);
                unsigned y3 = __shfl_xor(X3, 32);
                const int kc = 2 * s + c2;
                pw[kc][0] = hl ? y2 : X0;
                pw[kc][1] = hl ? y3 : X1;
                pw[kc][2] = hl ? X2 : y0;
                pw[kc][3] = hl ? X3 : y1;
            }
        // --- O^T += V^T · P^T ---
#pragma unroll
        for (int kc = 0; kc < 4; ++kc) {
            uintv4 u;
            u.x = pw[kc][0]; u.y = pw[kc][1]; u.z = pw[kc][2]; u.w = pw[kc][3];
            bf16x8 pf = __builtin_bit_cast(bf16x8, u);
            const unsigned short* vp = vb + (size_t)lq * 2048 + 64 * kt + 16 * kc + kofs;
#pragma unroll
            for (int dt = 0; dt < 4; ++dt) {
                bf16x8 vf = *reinterpret_cast<const bf16x8*>(vp + (size_t)(32 * dt) * 2048);
                O[dt] = __builtin_amdgcn_mfma_f32_32x32x16_bf16(vf, pf, O[dt], 0, 0, 0);
            }
        }
    }
    // --- epilogue: O[d][q] regs -> Ob[b][s=q0+lq][h*128 + d] ---
    float invl = 1.f / l;
    unsigned short* ob = Ob + ((size_t)(b * 2048 + q0 + lq)) * 2048 + h * 128;
#pragma unroll
    for (int dt = 0; dt < 4; ++dt)
#pragma unroll
        for (int g = 0; g < 4; ++g) {
            ushortv4 ov;
            ov.x = f2bf(O[dt][4 * g + 0] * invl);
            ov.y = f2bf(O[dt][4 * g + 1] * invl);
            ov.z = f2bf(O[dt][4 * g + 2] * invl);
            ov.w = f2bf(O[dt][4 * g + 3] * invl);
            *reinterpret_cast<ushortv4*>(ob + 32 * dt + 8 * g + 4 * hl) = ov;
        }
}

// ---------------- launch ----------------
extern "C" void kernel_launch(void* const* d_in, const int* in_sizes, int n_in,
                              void* d_out, int out_size, void* d_ws, size_t ws_size,
                              hipStream_t stream) {
    const float* x   = (const float*)d_in[0];
    const float* wq  = (const float*)d_in[1];
    const float* wkv = (const float*)d_in[2];
    const float* wo  = (const float*)d_in[3];

    float* out  = (float*)d_out;                 // (B,S,D) = 8388608
    float* Kout = out + 8388608;                 // (B,S,DH) = 524288
    float* Vout = Kout + 524288;

    char* ws = (char*)d_ws;
    unsigned short* xb   = (unsigned short*)(ws + 0);          // 16 MB
    unsigned short* wqb  = (unsigned short*)(ws + 16777216);   //  8 MB
    unsigned short* wkvT = (unsigned short*)(ws + 25165824);   //  1 MB
    unsigned short* wob  = (unsigned short*)(ws + 26214400);   //  8 MB
    float*          KVf  = (float*)(ws + 34603008);            //  4 MB
    float*          Qf   = (float*)(ws + 38797312);            // 32 MB
    unsigned short* Qb   = (unsigned short*)(ws + 0);          // 16 MB (aliases xb)
    unsigned short* Kb   = (unsigned short*)(ws + 16777216);   //  1 MB (aliases wqb)
    unsigned short* Vt   = (unsigned short*)(ws + 17825792);   //  1 MB (aliases wqb)
    unsigned short* Ob   = (unsigned short*)(ws + 34603008);   // 16 MB (aliases KVf/Qf)

    cast_bf16_k<<<8192, 256, 0, stream>>>(x,  xb,  2097152);
    cast_bf16_k<<<4096, 256, 0, stream>>>(wq, wqb, 1048576);
    cast_bf16_k<<<4096, 256, 0, stream>>>(wo, wob, 1048576);
    cast_t_wkv_k<<<2048, 256, 0, stream>>>(wkv, wkvT);

    gemm_bt<<<dim3(2, 32),  256, 0, stream>>>(xb, wkvT, KVf, 4096, 256,  2048);
    gemm_bt<<<dim3(16, 32), 256, 0, stream>>>(xb, wqb,  Qf,  4096, 2048, 2048);

    rope_pack_k<<<4096, 256, 0, stream>>>(Qf, KVf, Qb, Kb, Vt, Kout, Vout);

    attn_k<<<dim3(16, 16, 2), 256, 0, stream>>>(Qb, Kb, Vt, Ob);

    gemm_bt<<<dim3(16, 32), 256, 0, stream>>>(Ob, wob, out, 4096, 2048, 2048);
}

// Round 4
// 433.467 us; speedup vs baseline: 1.8117x; 1.1073x over previous
//
#include <hip/hip_runtime.h>
#include <hip/hip_bf16.h>
#include <cstdint>

// Problem constants: B=2, S=2048, D=2048, H=16, DH=128, past_length=0 (fixed).

typedef __attribute__((ext_vector_type(8))) __bf16 bf16x8;
typedef __attribute__((ext_vector_type(4))) float f32x4;
typedef __attribute__((ext_vector_type(16))) float f32x16;
typedef __attribute__((ext_vector_type(4))) float floatv4;
typedef __attribute__((ext_vector_type(4))) unsigned short ushortv4;
typedef __attribute__((ext_vector_type(4))) unsigned int uintv4;

__device__ __forceinline__ unsigned short f2bf(float f) {
    union { float f; unsigned u; } v; v.f = f;
    unsigned r = v.u + 0x7fffu + ((v.u >> 16) & 1u);
    return (unsigned short)(r >> 16);
}

__device__ __forceinline__ unsigned pk2(float a, float b) {
    return (unsigned)f2bf(a) | ((unsigned)f2bf(b) << 16);
}

__device__ __forceinline__ f32x16 zero16() {
    f32x16 z;
#pragma unroll
    for (int i = 0; i < 16; ++i) z[i] = 0.f;
    return z;
}

// global -> LDS async copy, 16B per lane.
#define GLL16(g, l)                                                                   \
    __builtin_amdgcn_global_load_lds(                                                 \
        (const __attribute__((address_space(1))) void*)(uintptr_t)(g),                \
        (__attribute__((address_space(3))) void*)(unsigned)(uintptr_t)(l), 16, 0, 0)

// ---------------- cast kernels ----------------
__global__ __launch_bounds__(256) void cast_bf16_k(const float* __restrict__ src,
                                                   unsigned short* __restrict__ dst, int n4) {
    int i = blockIdx.x * 256 + threadIdx.x;
    if (i >= n4) return;
    floatv4 v = reinterpret_cast<const floatv4*>(src)[i];
    ushortv4 o;
    o.x = f2bf(v.x); o.y = f2bf(v.y); o.z = f2bf(v.z); o.w = f2bf(v.w);
    reinterpret_cast<ushortv4*>(dst)[i] = o;
}

// wkv (2048 x 256) f32 -> wkvT (256 x 2048) bf16
__global__ __launch_bounds__(256) void cast_t_wkv_k(const float* __restrict__ src,
                                                    unsigned short* __restrict__ dst) {
    int i = blockIdx.x * 256 + threadIdx.x;  // 0..524287
    int k = i >> 8, j = i & 255;
    dst[j * 2048 + k] = f2bf(src[i]);
}

// ---------------- BT GEMM: C[M][N] = A[M][K] * B[N][K]^T (bf16 in, f32 out) -------
__global__ __launch_bounds__(256) void gemm_bt(const unsigned short* __restrict__ A,
                                               const unsigned short* __restrict__ B,
                                               float* __restrict__ C,
                                               int M, int N, int K) {
    __shared__ __align__(16) unsigned short As[4096];  // [128][32]
    __shared__ __align__(16) unsigned short Bs[4096];
    const int tid  = threadIdx.x;
    const int lane = tid & 63;
    const int wid  = tid >> 6;
    const int wr   = wid >> 1;
    const int wc   = wid & 1;
    const size_t row0 = (size_t)blockIdx.y * 128;
    const size_t col0 = (size_t)blockIdx.x * 128;
    f32x4 acc[4][4];
#pragma unroll
    for (int m = 0; m < 4; ++m)
#pragma unroll
        for (int n = 0; n < 4; ++n) acc[m][n] = (f32x4){0.f, 0.f, 0.f, 0.f};

    const int srow = tid >> 2;
    const int scol = (tid & 3) << 3;
    const unsigned short* Ag = A + (row0 + srow) * (size_t)K + scol;
    const unsigned short* Bg = B + (col0 + srow) * (size_t)K + scol;
    unsigned short* AsW = &As[wid << 9];
    unsigned short* BsW = &Bs[wid << 9];

    const int lrow = lane & 15;
    const int lk   = (lane >> 4) << 3;

    for (int k0 = 0; k0 < K; k0 += 32) {
        GLL16(Ag + k0, AsW);
        GLL16(Ag + k0 + (size_t)64 * K, AsW + 2048);
        GLL16(Bg + k0, BsW);
        GLL16(Bg + k0 + (size_t)64 * K, BsW + 2048);
        __syncthreads();
        bf16x8 af[4], bfr[4];
#pragma unroll
        for (int m = 0; m < 4; ++m)
            af[m] = *reinterpret_cast<const bf16x8*>(&As[(wr * 64 + m * 16 + lrow) * 32 + lk]);
#pragma unroll
        for (int n = 0; n < 4; ++n)
            bfr[n] = *reinterpret_cast<const bf16x8*>(&Bs[(wc * 64 + n * 16 + lrow) * 32 + lk]);
#pragma unroll
        for (int m = 0; m < 4; ++m)
#pragma unroll
            for (int n = 0; n < 4; ++n)
                acc[m][n] = __builtin_amdgcn_mfma_f32_16x16x32_bf16(af[m], bfr[n], acc[m][n], 0, 0, 0);
        __syncthreads();
    }
    const size_t orow0 = row0 + wr * 64 + ((lane >> 4) << 2);
    const size_t ocol  = col0 + wc * 64 + lrow;
#pragma unroll
    for (int m = 0; m < 4; ++m)
#pragma unroll
        for (int n = 0; n < 4; ++n)
#pragma unroll
            for (int r = 0; r < 4; ++r)
                C[(orow0 + m * 16 + r) * (size_t)N + ocol + n * 16] = acc[m][n][r];
}

// ---------------- RoPE + pack (round-2-exact) ----------------
__global__ __launch_bounds__(256) void rope_pack_k(const float* __restrict__ Qf,
                                                   const float* __restrict__ KVf,
                                                   unsigned short* __restrict__ Qb,
                                                   unsigned short* __restrict__ Kb,
                                                   unsigned short* __restrict__ Vt,
                                                   float* __restrict__ Kout,
                                                   float* __restrict__ Vout) {
    const int row = blockIdx.x;      // b*2048 + s
    const int b = row >> 11;
    const int s = row & 2047;
    const int t = threadIdx.x;
    const float* qrow = Qf + (size_t)row * 2048;
#pragma unroll
    for (int it = 0; it < 4; ++it) {
        int p = t + it * 256;        // pair index 0..1023
        int h = p >> 6;
        int i = p & 63;
        float fr  = exp2f(-(float)i * 0.20762050593045858f);  // 10000^(-i/64)
        float ang = (float)s * fr;
        float sn, c;
        sincosf(ang, &sn, &c);
        float x1 = qrow[h * 128 + i];
        float x2 = qrow[h * 128 + i + 64];
        size_t qb = (((size_t)(b * 16 + h)) * 2048 + s) * 128;
        Qb[qb + i]      = f2bf(x1 * c - x2 * sn);
        Qb[qb + i + 64] = f2bf(x2 * c + x1 * sn);
    }
    const float* kvrow = KVf + (size_t)row * 256;
    if (t < 128) {
        float kv = kvrow[t];
        float vv = kvrow[128 + t];
        Kout[(size_t)row * 128 + t] = kv;
        Vout[(size_t)row * 128 + t] = vv;
        Vt[((size_t)(b * 128 + t)) * 2048 + s] = f2bf(vv);
    }
    if (t < 64) {
        float fr  = exp2f(-(float)t * 0.20762050593045858f);
        float ang = (float)s * fr;
        float sn, c;
        sincosf(ang, &sn, &c);
        float x1 = kvrow[t];
        float x2 = kvrow[t + 64];
        size_t ko = ((size_t)b * 2048 + s) * 128;
        Kb[ko + t]      = f2bf(x1 * c - x2 * sn);
        Kb[ko + t + 64] = f2bf(x2 * c + x1 * sn);
    }
}

// ---------------- causal flash attention (MQA), wave-independent, reg-dbuf -------
// SINGLE change vs the passed round-2 kernel: per 64-key tile, V(kt) loads are
// issued into the just-freed K register buffer and K(kt+1) into the other buffer
// BEFORE the softmax VALU phase, so global-load latency hides under VALU (T14).
// Softmax/pack internals are round-2-exact (unconditional rescale, f2bf pack).
__global__ __launch_bounds__(256, 2) void attn_k(const unsigned short* __restrict__ Qb,
                                                 const unsigned short* __restrict__ Kb,
                                                 const unsigned short* __restrict__ Vt,
                                                 unsigned short* __restrict__ Ob) {
    const int h = blockIdx.y, b = blockIdx.z;
    const int lane = threadIdx.x & 63;
    const int w = threadIdx.x >> 6;
    const int tb = blockIdx.x * 4 + w;       // 0..63
    const int t = b ? (63 - tb) : tb;        // complementary balance across batches
    const int q0 = t * 32;
    const int lq = lane & 31;                // q column (C/D col = lane&31)
    const int hl = lane >> 5;                // lane half
    const int kofs = hl * 8;                 // k-dim offset inside a 16-chunk

    const unsigned short* qp = Qb + (((size_t)(b * 16 + h)) * 2048 + q0 + lq) * 128 + kofs;
    bf16x8 qf[8];
#pragma unroll
    for (int c = 0; c < 8; ++c)
        qf[c] = *reinterpret_cast<const bf16x8*>(qp + 16 * c);

    f32x16 O[4];
#pragma unroll
    for (int dt = 0; dt < 4; ++dt) O[dt] = zero16();
    float m = -1e30f, l = 0.f;

    const int nkt = t / 2 + 1;               // number of 64-key tiles
    const unsigned short* kb = Kb + (size_t)b * 2048 * 128;
    const unsigned short* vb = Vt + (size_t)b * 128 * 2048;
    const float csc = 0.12751782377892224f;  // (1/sqrt(128)) * log2(e)

    bf16x8 bufA[16], bufB[16];
    {   // prologue: K tile 0 -> bufA
        const unsigned short* kp = kb + (size_t)lq * 128 + kofs;
#pragma unroll
        for (int c = 0; c < 8; ++c) {
            bufA[c]     = *reinterpret_cast<const bf16x8*>(kp + 16 * c);
            bufA[8 + c] = *reinterpret_cast<const bf16x8*>(kp + 32 * 128 + 16 * c);
        }
    }

    int kt = 0;
    auto STEP = [&](bf16x8 (&Kc)[16], bf16x8 (&Kn)[16]) {
        // --- S^T = K · Q^T ---
        f32x16 S0 = zero16(), S1 = zero16();
#pragma unroll
        for (int c = 0; c < 8; ++c) {
            S0 = __builtin_amdgcn_mfma_f32_32x32x16_bf16(Kc[c],     qf[c], S0, 0, 0, 0);
            S1 = __builtin_amdgcn_mfma_f32_32x32x16_bf16(Kc[8 + c], qf[c], S1, 0, 0, 0);
        }
        // --- issue V(kt) into Kc (dead after the MFMAs above) ---
        const unsigned short* vp = vb + (size_t)lq * 2048 + 64 * kt + kofs;
#pragma unroll
        for (int dt = 0; dt < 4; ++dt)
#pragma unroll
            for (int kc = 0; kc < 4; ++kc)
                Kc[4 * dt + kc] =
                    *reinterpret_cast<const bf16x8*>(vp + (size_t)(32 * dt) * 2048 + 16 * kc);
        // --- issue K(kt+1) into Kn (clamped; last-iter loads are dead) ---
        const int ktn = (kt + 1 < nkt) ? (kt + 1) : kt;
        const unsigned short* kp = kb + (size_t)(64 * ktn + lq) * 128 + kofs;
#pragma unroll
        for (int c = 0; c < 8; ++c) {
            Kn[c]     = *reinterpret_cast<const bf16x8*>(kp + 16 * c);
            Kn[8 + c] = *reinterpret_cast<const bf16x8*>(kp + 32 * 128 + 16 * c);
        }
        // --- softmax (round-2-exact) — overlaps the loads above ---
        float sc[32];
        const bool lastt = (kt == nkt - 1);
#pragma unroll
        for (int s = 0; s < 2; ++s)
#pragma unroll
            for (int r = 0; r < 16; ++r) {
                float v = (s ? S1[r] : S0[r]) * csc;
                if (lastt) {
                    int key = 64 * kt + 32 * s + (r & 3) + 8 * (r >> 2) + 4 * hl;
                    if (key > q0 + lq) v = -3.0e38f;
                }
                sc[16 * s + r] = v;
            }
        float tm[16];
#pragma unroll
        for (int i = 0; i < 16; ++i) tm[i] = fmaxf(sc[i], sc[i + 16]);
#pragma unroll
        for (int st = 8; st > 0; st >>= 1)
#pragma unroll
            for (int i = 0; i < st; ++i) tm[i] = fmaxf(tm[i], tm[i + st]);
        float mt = fmaxf(tm[0], __shfl_xor(tm[0], 32));
        float mn = fmaxf(m, mt);
        float corr = __builtin_amdgcn_exp2f(m - mn);
        m = mn;
#pragma unroll
        for (int i = 0; i < 32; ++i) sc[i] = __builtin_amdgcn_exp2f(sc[i] - mn);
        float ts[16];
#pragma unroll
        for (int i = 0; i < 16; ++i) ts[i] = sc[i] + sc[i + 16];
#pragma unroll
        for (int st = 8; st > 0; st >>= 1)
#pragma unroll
            for (int i = 0; i < st; ++i) ts[i] += ts[i + st];
        l = l * corr + ts[0] + __shfl_xor(ts[0], 32);
#pragma unroll
        for (int dt = 0; dt < 4; ++dt)
#pragma unroll
            for (int r = 0; r < 16; ++r) O[dt][r] *= corr;
        // --- pack P into PV B-fragments (round-2-exact) ---
        unsigned pw[4][4];
#pragma unroll
        for (int s = 0; s < 2; ++s)
#pragma unroll
            for (int c2 = 0; c2 < 2; ++c2) {
                const int rb = 16 * s + 8 * c2;
                unsigned X0 = pk2(sc[rb + 0], sc[rb + 1]);
                unsigned X1 = pk2(sc[rb + 2], sc[rb + 3]);
                unsigned X2 = pk2(sc[rb + 4], sc[rb + 5]);
                unsigned X3 = pk2(sc[rb + 6], sc[rb + 7]);
                unsigned y0 = __shfl_xor(X0, 32);
                unsigned y1 = __shfl_xor(X1, 32);
                unsigned y2 = __shfl_xor(X2, 32);
                unsigned y3 = __shfl_xor(X3, 32);
                const int kc = 2 * s + c2;
                pw[kc][0] = hl ? y2 : X0;
                pw[kc][1] = hl ? y3 : X1;
                pw[kc][2] = hl ? X2 : y0;
                pw[kc][3] = hl ? X3 : y1;
            }
        // --- O^T += V^T · P^T (V regs = Kc) ---
#pragma unroll
        for (int kc = 0; kc < 4; ++kc) {
            uintv4 u;
            u.x = pw[kc][0]; u.y = pw[kc][1]; u.z = pw[kc][2]; u.w = pw[kc][3];
            bf16x8 pf = __builtin_bit_cast(bf16x8, u);
#pragma unroll
            for (int dt = 0; dt < 4; ++dt)
                O[dt] = __builtin_amdgcn_mfma_f32_32x32x16_bf16(Kc[4 * dt + kc], pf, O[dt], 0, 0, 0);
        }
    };

    for (;;) {
        STEP(bufA, bufB);
        if (++kt == nkt) break;
        STEP(bufB, bufA);
        if (++kt == nkt) break;
    }

    // --- epilogue: O[d][q] regs -> Ob[b][s=q0+lq][h*128 + d] ---
    float invl = 1.f / l;
    unsigned short* ob = Ob + ((size_t)(b * 2048 + q0 + lq)) * 2048 + h * 128;
#pragma unroll
    for (int dt = 0; dt < 4; ++dt)
#pragma unroll
        for (int g = 0; g < 4; ++g) {
            ushortv4 ov;
            ov.x = f2bf(O[dt][4 * g + 0] * invl);
            ov.y = f2bf(O[dt][4 * g + 1] * invl);
            ov.z = f2bf(O[dt][4 * g + 2] * invl);
            ov.w = f2bf(O[dt][4 * g + 3] * invl);
            *reinterpret_cast<ushortv4*>(ob + 32 * dt + 8 * g + 4 * hl) = ov;
        }
}

// ---------------- launch ----------------
extern "C" void kernel_launch(void* const* d_in, const int* in_sizes, int n_in,
                              void* d_out, int out_size, void* d_ws, size_t ws_size,
                              hipStream_t stream) {
    const float* x   = (const float*)d_in[0];
    const float* wq  = (const float*)d_in[1];
    const float* wkv = (const float*)d_in[2];
    const float* wo  = (const float*)d_in[3];

    float* out  = (float*)d_out;                 // (B,S,D) = 8388608
    float* Kout = out + 8388608;                 // (B,S,DH) = 524288
    float* Vout = Kout + 524288;

    char* ws = (char*)d_ws;
    unsigned short* xb   = (unsigned short*)(ws + 0);          // 16 MB
    unsigned short* wqb  = (unsigned short*)(ws + 16777216);   //  8 MB
    unsigned short* wkvT = (unsigned short*)(ws + 25165824);   //  1 MB
    unsigned short* wob  = (unsigned short*)(ws + 26214400);   //  8 MB
    float*          KVf  = (float*)(ws + 34603008);            //  4 MB
    float*          Qf   = (float*)(ws + 38797312);            // 32 MB
    unsigned short* Qb   = (unsigned short*)(ws + 0);          // 16 MB (aliases xb)
    unsigned short* Kb   = (unsigned short*)(ws + 16777216);   //  1 MB (aliases wqb)
    unsigned short* Vt   = (unsigned short*)(ws + 17825792);   //  1 MB (aliases wqb)
    unsigned short* Ob   = (unsigned short*)(ws + 34603008);   // 16 MB (aliases KVf/Qf)

    cast_bf16_k<<<8192, 256, 0, stream>>>(x,  xb,  2097152);
    cast_bf16_k<<<4096, 256, 0, stream>>>(wq, wqb, 1048576);
    cast_bf16_k<<<4096, 256, 0, stream>>>(wo, wob, 1048576);
    cast_t_wkv_k<<<2048, 256, 0, stream>>>(wkv, wkvT);

    gemm_bt<<<dim3(2, 32),  256, 0, stream>>>(xb, wkvT, KVf, 4096, 256,  2048);
    gemm_bt<<<dim3(16, 32), 256, 0, stream>>>(xb, wqb,  Qf,  4096, 2048, 2048);

    rope_pack_k<<<4096, 256, 0, stream>>>(Qf, KVf, Qb, Kb, Vt, Kout, Vout);

    attn_k<<<dim3(16, 16, 2), 256, 0, stream>>>(Qb, Kb, Vt, Ob);

    gemm_bt<<<dim3(16, 32), 256, 0, stream>>>(Ob, wob, out, 4096, 2048, 2048);
}

// Round 5
// 416.568 us; speedup vs baseline: 1.8852x; 1.0406x over previous
//
#include <hip/hip_runtime.h>
#include <hip/hip_bf16.h>
#include <cstdint>

// Problem constants: B=2, S=2048, D=2048, H=16, DH=128, past_length=0 (fixed).

typedef __attribute__((ext_vector_type(8))) __bf16 bf16x8;
typedef __attribute__((ext_vector_type(4))) float f32x4;
typedef __attribute__((ext_vector_type(16))) float f32x16;
typedef __attribute__((ext_vector_type(4))) float floatv4;
typedef __attribute__((ext_vector_type(4))) unsigned short ushortv4;
typedef __attribute__((ext_vector_type(4))) unsigned int uintv4;

__device__ __forceinline__ unsigned short f2bf(float f) {
    union { float f; unsigned u; } v; v.f = f;
    unsigned r = v.u + 0x7fffu + ((v.u >> 16) & 1u);
    return (unsigned short)(r >> 16);
}

__device__ __forceinline__ unsigned pk2(float a, float b) {
    return (unsigned)f2bf(a) | ((unsigned)f2bf(b) << 16);
}

__device__ __forceinline__ f32x16 zero16() {
    f32x16 z;
#pragma unroll
    for (int i = 0; i < 16; ++i) z[i] = 0.f;
    return z;
}

// global -> LDS async copy, 16B per lane.
#define GLL16(g, l)                                                                   \
    __builtin_amdgcn_global_load_lds(                                                 \
        (const __attribute__((address_space(1))) void*)(uintptr_t)(g),                \
        (__attribute__((address_space(3))) void*)(unsigned)(uintptr_t)(l), 16, 0, 0)

// ---------------- cast kernels ----------------
__global__ __launch_bounds__(256) void cast_bf16_k(const float* __restrict__ src,
                                                   unsigned short* __restrict__ dst, int n4) {
    int i = blockIdx.x * 256 + threadIdx.x;
    if (i >= n4) return;
    floatv4 v = reinterpret_cast<const floatv4*>(src)[i];
    ushortv4 o;
    o.x = f2bf(v.x); o.y = f2bf(v.y); o.z = f2bf(v.z); o.w = f2bf(v.w);
    reinterpret_cast<ushortv4*>(dst)[i] = o;
}

// wkv (2048 x 256) f32 -> wkvT (256 x 2048) bf16
__global__ __launch_bounds__(256) void cast_t_wkv_k(const float* __restrict__ src,
                                                    unsigned short* __restrict__ dst) {
    int i = blockIdx.x * 256 + threadIdx.x;  // 0..524287
    int k = i >> 8, j = i & 255;
    dst[j * 2048 + k] = f2bf(src[i]);
}

// ---------------- BT GEMM: C[M][N] = A[M][K] * B[N][K]^T (bf16 in, f32 out) -------
__global__ __launch_bounds__(256) void gemm_bt(const unsigned short* __restrict__ A,
                                               const unsigned short* __restrict__ B,
                                               float* __restrict__ C,
                                               int M, int N, int K) {
    __shared__ __align__(16) unsigned short As[4096];  // [128][32]
    __shared__ __align__(16) unsigned short Bs[4096];
    const int tid  = threadIdx.x;
    const int lane = tid & 63;
    const int wid  = tid >> 6;
    const int wr   = wid >> 1;
    const int wc   = wid & 1;
    const size_t row0 = (size_t)blockIdx.y * 128;
    const size_t col0 = (size_t)blockIdx.x * 128;
    f32x4 acc[4][4];
#pragma unroll
    for (int m = 0; m < 4; ++m)
#pragma unroll
        for (int n = 0; n < 4; ++n) acc[m][n] = (f32x4){0.f, 0.f, 0.f, 0.f};

    const int srow = tid >> 2;
    const int scol = (tid & 3) << 3;
    const unsigned short* Ag = A + (row0 + srow) * (size_t)K + scol;
    const unsigned short* Bg = B + (col0 + srow) * (size_t)K + scol;
    unsigned short* AsW = &As[wid << 9];
    unsigned short* BsW = &Bs[wid << 9];

    const int lrow = lane & 15;
    const int lk   = (lane >> 4) << 3;

    for (int k0 = 0; k0 < K; k0 += 32) {
        GLL16(Ag + k0, AsW);
        GLL16(Ag + k0 + (size_t)64 * K, AsW + 2048);
        GLL16(Bg + k0, BsW);
        GLL16(Bg + k0 + (size_t)64 * K, BsW + 2048);
        __syncthreads();
        bf16x8 af[4], bfr[4];
#pragma unroll
        for (int m = 0; m < 4; ++m)
            af[m] = *reinterpret_cast<const bf16x8*>(&As[(wr * 64 + m * 16 + lrow) * 32 + lk]);
#pragma unroll
        for (int n = 0; n < 4; ++n)
            bfr[n] = *reinterpret_cast<const bf16x8*>(&Bs[(wc * 64 + n * 16 + lrow) * 32 + lk]);
#pragma unroll
        for (int m = 0; m < 4; ++m)
#pragma unroll
            for (int n = 0; n < 4; ++n)
                acc[m][n] = __builtin_amdgcn_mfma_f32_16x16x32_bf16(af[m], bfr[n], acc[m][n], 0, 0, 0);
        __syncthreads();
    }
    const size_t orow0 = row0 + wr * 64 + ((lane >> 4) << 2);
    const size_t ocol  = col0 + wc * 64 + lrow;
#pragma unroll
    for (int m = 0; m < 4; ++m)
#pragma unroll
        for (int n = 0; n < 4; ++n)
#pragma unroll
            for (int r = 0; r < 4; ++r)
                C[(orow0 + m * 16 + r) * (size_t)N + ocol + n * 16] = acc[m][n][r];
}

// ---------------- RoPE + pack (unchanged, passed round 4) ----------------
__global__ __launch_bounds__(256) void rope_pack_k(const float* __restrict__ Qf,
                                                   const float* __restrict__ KVf,
                                                   unsigned short* __restrict__ Qb,
                                                   unsigned short* __restrict__ Kb,
                                                   unsigned short* __restrict__ Vt,
                                                   float* __restrict__ Kout,
                                                   float* __restrict__ Vout) {
    const int row = blockIdx.x;      // b*2048 + s
    const int b = row >> 11;
    const int s = row & 2047;
    const int t = threadIdx.x;
    const float* qrow = Qf + (size_t)row * 2048;
#pragma unroll
    for (int it = 0; it < 4; ++it) {
        int p = t + it * 256;        // pair index 0..1023
        int h = p >> 6;
        int i = p & 63;
        float fr  = exp2f(-(float)i * 0.20762050593045858f);  // 10000^(-i/64)
        float ang = (float)s * fr;
        float sn, c;
        sincosf(ang, &sn, &c);
        float x1 = qrow[h * 128 + i];
        float x2 = qrow[h * 128 + i + 64];
        size_t qb = (((size_t)(b * 16 + h)) * 2048 + s) * 128;
        Qb[qb + i]      = f2bf(x1 * c - x2 * sn);
        Qb[qb + i + 64] = f2bf(x2 * c + x1 * sn);
    }
    const float* kvrow = KVf + (size_t)row * 256;
    if (t < 128) {
        float kv = kvrow[t];
        float vv = kvrow[128 + t];
        Kout[(size_t)row * 128 + t] = kv;
        Vout[(size_t)row * 128 + t] = vv;
        Vt[((size_t)(b * 128 + t)) * 2048 + s] = f2bf(vv);
    }
    if (t < 64) {
        float fr  = exp2f(-(float)t * 0.20762050593045858f);
        float ang = (float)s * fr;
        float sn, c;
        sincosf(ang, &sn, &c);
        float x1 = kvrow[t];
        float x2 = kvrow[t + 64];
        size_t ko = ((size_t)b * 2048 + s) * 128;
        Kb[ko + t]      = f2bf(x1 * c - x2 * sn);
        Kb[ko + t + 64] = f2bf(x2 * c + x1 * sn);
    }
}

// ---------------- causal flash attention (MQA), 2-way key-split per q-tile -------
// CHANGE vs passed round 4: each 32-row q-tile is processed by TWO waves splitting
// the key-tile range (A: [0,nh), B: [nh,nkt) incl. masked diagonal); partials merge
// via LDS + one barrier with online-softmax combine. Waves 2048->4096 (4/SIMD) for
// TLP latency hiding. Intra-block balance: tiles (x, 63-x) => ~constant block work.
// STEP internals byte-equivalent to round 4.
__global__ __launch_bounds__(256, 2) void attn_k(const unsigned short* __restrict__ Qb,
                                                 const unsigned short* __restrict__ Kb,
                                                 const unsigned short* __restrict__ Vt,
                                                 unsigned short* __restrict__ Ob) {
    const int h = blockIdx.y, b = blockIdx.z;
    const int lane = threadIdx.x & 63;
    const int w = threadIdx.x >> 6;
    const int pair = w >> 1;                 // which q-tile in this block
    const int role = w & 1;                  // 0 = first key half, 1 = second half
    const int t = pair ? (63 - blockIdx.x) : blockIdx.x;   // q-tile 0..63
    const int q0 = t * 32;
    const int lq = lane & 31;                // q column (C/D col = lane&31)
    const int hl = lane >> 5;                // lane half
    const int kofs = hl * 8;                 // k-dim offset inside a 16-chunk

    __shared__ float Olds[2][4][16][64];     // 32 KB partial-O exchange
    __shared__ float mlds[2][32];
    __shared__ float llds[2][32];

    const unsigned short* qp = Qb + (((size_t)(b * 16 + h)) * 2048 + q0 + lq) * 128 + kofs;
    bf16x8 qf[8];
#pragma unroll
    for (int c = 0; c < 8; ++c)
        qf[c] = *reinterpret_cast<const bf16x8*>(qp + 16 * c);

    f32x16 O[4];
#pragma unroll
    for (int dt = 0; dt < 4; ++dt) O[dt] = zero16();
    float m = -1e30f, l = 0.f;

    const int nkt = t / 2 + 1;               // total 64-key tiles for this q-tile
    const int nh  = (nkt + 1) / 2;           // A gets ceil (B's mask tile costs more)
    const int ks  = role ? nh : 0;
    const int ke  = role ? nkt : nh;
    const unsigned short* kb = Kb + (size_t)b * 2048 * 128;
    const unsigned short* vb = Vt + (size_t)b * 128 * 2048;
    const float csc = 0.12751782377892224f;  // (1/sqrt(128)) * log2(e)

    bf16x8 bufA[16], bufB[16];
    if (ks < ke) {   // prologue: K tile ks
        const unsigned short* kp = kb + (size_t)(64 * ks + lq) * 128 + kofs;
#pragma unroll
        for (int c = 0; c < 8; ++c) {
            bufA[c]     = *reinterpret_cast<const bf16x8*>(kp + 16 * c);
            bufA[8 + c] = *reinterpret_cast<const bf16x8*>(kp + 32 * 128 + 16 * c);
        }
    }

    int kt = ks;
    auto STEP = [&](bf16x8 (&Kc)[16], bf16x8 (&Kn)[16]) {
        // --- S^T = K · Q^T ---
        f32x16 S0 = zero16(), S1 = zero16();
#pragma unroll
        for (int c = 0; c < 8; ++c) {
            S0 = __builtin_amdgcn_mfma_f32_32x32x16_bf16(Kc[c],     qf[c], S0, 0, 0, 0);
            S1 = __builtin_amdgcn_mfma_f32_32x32x16_bf16(Kc[8 + c], qf[c], S1, 0, 0, 0);
        }
        // --- issue V(kt) into Kc (dead after the MFMAs above) ---
        const unsigned short* vp = vb + (size_t)lq * 2048 + 64 * kt + kofs;
#pragma unroll
        for (int dt = 0; dt < 4; ++dt)
#pragma unroll
            for (int kc = 0; kc < 4; ++kc)
                Kc[4 * dt + kc] =
                    *reinterpret_cast<const bf16x8*>(vp + (size_t)(32 * dt) * 2048 + 16 * kc);
        // --- issue K(kt+1) into Kn (clamped; last-iter loads are dead) ---
        const int ktn = (kt + 1 < ke) ? (kt + 1) : kt;
        const unsigned short* kp = kb + (size_t)(64 * ktn + lq) * 128 + kofs;
#pragma unroll
        for (int c = 0; c < 8; ++c) {
            Kn[c]     = *reinterpret_cast<const bf16x8*>(kp + 16 * c);
            Kn[8 + c] = *reinterpret_cast<const bf16x8*>(kp + 32 * 128 + 16 * c);
        }
        // --- softmax — overlaps the loads above ---
        float sc[32];
        const bool lastt = (kt == nkt - 1);  // global diagonal tile
#pragma unroll
        for (int s = 0; s < 2; ++s)
#pragma unroll
            for (int r = 0; r < 16; ++r) {
                float v = (s ? S1[r] : S0[r]) * csc;
                if (lastt) {
                    int key = 64 * kt + 32 * s + (r & 3) + 8 * (r >> 2) + 4 * hl;
                    if (key > q0 + lq) v = -3.0e38f;
                }
                sc[16 * s + r] = v;
            }
        float tm[16];
#pragma unroll
        for (int i = 0; i < 16; ++i) tm[i] = fmaxf(sc[i], sc[i + 16]);
#pragma unroll
        for (int st = 8; st > 0; st >>= 1)
#pragma unroll
            for (int i = 0; i < st; ++i) tm[i] = fmaxf(tm[i], tm[i + st]);
        float mt = fmaxf(tm[0], __shfl_xor(tm[0], 32));
        float mn = fmaxf(m, mt);
        float corr = __builtin_amdgcn_exp2f(m - mn);
        m = mn;
#pragma unroll
        for (int i = 0; i < 32; ++i) sc[i] = __builtin_amdgcn_exp2f(sc[i] - mn);
        float ts[16];
#pragma unroll
        for (int i = 0; i < 16; ++i) ts[i] = sc[i] + sc[i + 16];
#pragma unroll
        for (int st = 8; st > 0; st >>= 1)
#pragma unroll
            for (int i = 0; i < st; ++i) ts[i] += ts[i + st];
        l = l * corr + ts[0] + __shfl_xor(ts[0], 32);
#pragma unroll
        for (int dt = 0; dt < 4; ++dt)
#pragma unroll
            for (int r = 0; r < 16; ++r) O[dt][r] *= corr;
        // --- pack P into PV B-fragments ---
        unsigned pw[4][4];
#pragma unroll
        for (int s = 0; s < 2; ++s)
#pragma unroll
            for (int c2 = 0; c2 < 2; ++c2) {
                const int rb = 16 * s + 8 * c2;
                unsigned X0 = pk2(sc[rb + 0], sc[rb + 1]);
                unsigned X1 = pk2(sc[rb + 2], sc[rb + 3]);
                unsigned X2 = pk2(sc[rb + 4], sc[rb + 5]);
                unsigned X3 = pk2(sc[rb + 6], sc[rb + 7]);
                unsigned y0 = __shfl_xor(X0, 32);
                unsigned y1 = __shfl_xor(X1, 32);
                unsigned y2 = __shfl_xor(X2, 32);
                unsigned y3 = __shfl_xor(X3, 32);
                const int kc = 2 * s + c2;
                pw[kc][0] = hl ? y2 : X0;
                pw[kc][1] = hl ? y3 : X1;
                pw[kc][2] = hl ? X2 : y0;
                pw[kc][3] = hl ? X3 : y1;
            }
        // --- O^T += V^T · P^T (V regs = Kc) ---
#pragma unroll
        for (int kc = 0; kc < 4; ++kc) {
            uintv4 u;
            u.x = pw[kc][0]; u.y = pw[kc][1]; u.z = pw[kc][2]; u.w = pw[kc][3];
            bf16x8 pf = __builtin_bit_cast(bf16x8, u);
#pragma unroll
            for (int dt = 0; dt < 4; ++dt)
                O[dt] = __builtin_amdgcn_mfma_f32_32x32x16_bf16(Kc[4 * dt + kc], pf, O[dt], 0, 0, 0);
        }
    };

    while (kt < ke) {
        STEP(bufA, bufB);
        if (++kt == ke) break;
        STEP(bufB, bufA);
        ++kt;
    }

    // --- merge the two key-halves of each q-tile ---
    if (role == 0) {
#pragma unroll
        for (int dt = 0; dt < 4; ++dt)
#pragma unroll
            for (int r = 0; r < 16; ++r)
                Olds[pair][dt][r][lane] = O[dt][r];
        if (lane < 32) { mlds[pair][lane] = m; llds[pair][lane] = l; }
    }
    __syncthreads();
    if (role == 1) {
        float mA = mlds[pair][lq];
        float lA = llds[pair][lq];
        float ms = fmaxf(mA, m);
        float sA = __builtin_amdgcn_exp2f(mA - ms);
        float sB = __builtin_amdgcn_exp2f(m - ms);
        float invl = 1.f / (lA * sA + l * sB);
        unsigned short* ob = Ob + ((size_t)(b * 2048 + q0 + lq)) * 2048 + h * 128;
#pragma unroll
        for (int dt = 0; dt < 4; ++dt)
#pragma unroll
            for (int g = 0; g < 4; ++g) {
                ushortv4 ov;
#pragma unroll
                for (int j = 0; j < 4; ++j) {
                    int r = 4 * g + j;
                    float val = (Olds[pair][dt][r][lane] * sA + O[dt][r] * sB) * invl;
                    ((unsigned short*)&ov)[j] = f2bf(val);
                }
                *reinterpret_cast<ushortv4*>(ob + 32 * dt + 8 * g + 4 * hl) = ov;
            }
    }
}

// ---------------- launch ----------------
extern "C" void kernel_launch(void* const* d_in, const int* in_sizes, int n_in,
                              void* d_out, int out_size, void* d_ws, size_t ws_size,
                              hipStream_t stream) {
    const float* x   = (const float*)d_in[0];
    const float* wq  = (const float*)d_in[1];
    const float* wkv = (const float*)d_in[2];
    const float* wo  = (const float*)d_in[3];

    float* out  = (float*)d_out;                 // (B,S,D) = 8388608
    float* Kout = out + 8388608;                 // (B,S,DH) = 524288
    float* Vout = Kout + 524288;

    char* ws = (char*)d_ws;
    unsigned short* xb   = (unsigned short*)(ws + 0);          // 16 MB
    unsigned short* wqb  = (unsigned short*)(ws + 16777216);   //  8 MB
    unsigned short* wkvT = (unsigned short*)(ws + 25165824);   //  1 MB
    unsigned short* wob  = (unsigned short*)(ws + 26214400);   //  8 MB
    float*          KVf  = (float*)(ws + 34603008);            //  4 MB
    float*          Qf   = (float*)(ws + 38797312);            // 32 MB
    unsigned short* Qb   = (unsigned short*)(ws + 0);          // 16 MB (aliases xb)
    unsigned short* Kb   = (unsigned short*)(ws + 16777216);   //  1 MB (aliases wqb)
    unsigned short* Vt   = (unsigned short*)(ws + 17825792);   //  1 MB (aliases wqb)
    unsigned short* Ob   = (unsigned short*)(ws + 34603008);   // 16 MB (aliases KVf/Qf)

    cast_bf16_k<<<8192, 256, 0, stream>>>(x,  xb,  2097152);
    cast_bf16_k<<<4096, 256, 0, stream>>>(wq, wqb, 1048576);
    cast_bf16_k<<<4096, 256, 0, stream>>>(wo, wob, 1048576);
    cast_t_wkv_k<<<2048, 256, 0, stream>>>(wkv, wkvT);

    gemm_bt<<<dim3(2, 32),  256, 0, stream>>>(xb, wkvT, KVf, 4096, 256,  2048);
    gemm_bt<<<dim3(16, 32), 256, 0, stream>>>(xb, wqb,  Qf,  4096, 2048, 2048);

    rope_pack_k<<<4096, 256, 0, stream>>>(Qf, KVf, Qb, Kb, Vt, Kout, Vout);

    attn_k<<<dim3(32, 16, 2), 256, 0, stream>>>(Qb, Kb, Vt, Ob);

    gemm_bt<<<dim3(16, 32), 256, 0, stream>>>(Ob, wob, out, 4096, 2048, 2048);
}

// Round 7
// 386.627 us; speedup vs baseline: 2.0312x; 1.0774x over previous
//
#include <hip/hip_runtime.h>
#include <hip/hip_bf16.h>
#include <cstdint>

// Problem constants: B=2, S=2048, D=2048, H=16, DH=128, past_length=0 (fixed).

typedef __attribute__((ext_vector_type(8))) __bf16 bf16x8;
typedef __attribute__((ext_vector_type(4))) float f32x4;
typedef __attribute__((ext_vector_type(16))) float f32x16;
typedef __attribute__((ext_vector_type(4))) float floatv4;
typedef __attribute__((ext_vector_type(4))) unsigned short ushortv4;
typedef __attribute__((ext_vector_type(4))) unsigned int uintv4;

__device__ __forceinline__ unsigned short f2bf(float f) {
    union { float f; unsigned u; } v; v.f = f;
    unsigned r = v.u + 0x7fffu + ((v.u >> 16) & 1u);
    return (unsigned short)(r >> 16);
}

__device__ __forceinline__ unsigned pk2(float a, float b) {
    return (unsigned)f2bf(a) | ((unsigned)f2bf(b) << 16);
}

__device__ __forceinline__ f32x16 zero16() {
    f32x16 z;
#pragma unroll
    for (int i = 0; i < 16; ++i) z[i] = 0.f;
    return z;
}

// global -> LDS async copy, 16B per lane. LDS dest = wave-uniform base + lane*16;
// global source is per-lane (enables swizzled staging via pre-swizzled source).
#define GLL16(g, l)                                                                   \
    __builtin_amdgcn_global_load_lds(                                                 \
        (const __attribute__((address_space(1))) void*)(uintptr_t)(g),                \
        (__attribute__((address_space(3))) void*)(unsigned)(uintptr_t)(l), 16, 0, 0)

// ---------------- cast kernels ----------------
__global__ __launch_bounds__(256) void cast_bf16_k(const float* __restrict__ src,
                                                   unsigned short* __restrict__ dst, int n4) {
    int i = blockIdx.x * 256 + threadIdx.x;
    if (i >= n4) return;
    floatv4 v = reinterpret_cast<const floatv4*>(src)[i];
    ushortv4 o;
    o.x = f2bf(v.x); o.y = f2bf(v.y); o.z = f2bf(v.z); o.w = f2bf(v.w);
    reinterpret_cast<ushortv4*>(dst)[i] = o;
}

// wkv (2048 x 256) f32 -> wkvT (256 x 2048) bf16
__global__ __launch_bounds__(256) void cast_t_wkv_k(const float* __restrict__ src,
                                                    unsigned short* __restrict__ dst) {
    int i = blockIdx.x * 256 + threadIdx.x;  // 0..524287
    int k = i >> 8, j = i & 255;
    dst[j * 2048 + k] = f2bf(src[i]);
}

// ---------------- BT GEMM: C[M][N] = A[M][K] * B[N][K]^T (bf16 in, f32 out) -------
__global__ __launch_bounds__(256) void gemm_bt(const unsigned short* __restrict__ A,
                                               const unsigned short* __restrict__ B,
                                               float* __restrict__ C,
                                               int M, int N, int K) {
    __shared__ __align__(16) unsigned short As[4096];  // [128][32]
    __shared__ __align__(16) unsigned short Bs[4096];
    const int tid  = threadIdx.x;
    const int lane = tid & 63;
    const int wid  = tid >> 6;
    const int wr   = wid >> 1;
    const int wc   = wid & 1;
    const size_t row0 = (size_t)blockIdx.y * 128;
    const size_t col0 = (size_t)blockIdx.x * 128;
    f32x4 acc[4][4];
#pragma unroll
    for (int m = 0; m < 4; ++m)
#pragma unroll
        for (int n = 0; n < 4; ++n) acc[m][n] = (f32x4){0.f, 0.f, 0.f, 0.f};

    const int srow = tid >> 2;
    const int scol = (tid & 3) << 3;
    const unsigned short* Ag = A + (row0 + srow) * (size_t)K + scol;
    const unsigned short* Bg = B + (col0 + srow) * (size_t)K + scol;
    unsigned short* AsW = &As[wid << 9];
    unsigned short* BsW = &Bs[wid << 9];

    const int lrow = lane & 15;
    const int lk   = (lane >> 4) << 3;

    for (int k0 = 0; k0 < K; k0 += 32) {
        GLL16(Ag + k0, AsW);
        GLL16(Ag + k0 + (size_t)64 * K, AsW + 2048);
        GLL16(Bg + k0, BsW);
        GLL16(Bg + k0 + (size_t)64 * K, BsW + 2048);
        __syncthreads();
        bf16x8 af[4], bfr[4];
#pragma unroll
        for (int m = 0; m < 4; ++m)
            af[m] = *reinterpret_cast<const bf16x8*>(&As[(wr * 64 + m * 16 + lrow) * 32 + lk]);
#pragma unroll
        for (int n = 0; n < 4; ++n)
            bfr[n] = *reinterpret_cast<const bf16x8*>(&Bs[(wc * 64 + n * 16 + lrow) * 32 + lk]);
#pragma unroll
        for (int m = 0; m < 4; ++m)
#pragma unroll
            for (int n = 0; n < 4; ++n)
                acc[m][n] = __builtin_amdgcn_mfma_f32_16x16x32_bf16(af[m], bfr[n], acc[m][n], 0, 0, 0);
        __syncthreads();
    }
    const size_t orow0 = row0 + wr * 64 + ((lane >> 4) << 2);
    const size_t ocol  = col0 + wc * 64 + lrow;
#pragma unroll
    for (int m = 0; m < 4; ++m)
#pragma unroll
        for (int n = 0; n < 4; ++n)
#pragma unroll
            for (int r = 0; r < 4; ++r)
                C[(orow0 + m * 16 + r) * (size_t)N + ocol + n * 16] = acc[m][n][r];
}

// ---------------- RoPE + pack (unchanged, passed rounds 4/5) ----------------
__global__ __launch_bounds__(256) void rope_pack_k(const float* __restrict__ Qf,
                                                   const float* __restrict__ KVf,
                                                   unsigned short* __restrict__ Qb,
                                                   unsigned short* __restrict__ Kb,
                                                   unsigned short* __restrict__ Vt,
                                                   float* __restrict__ Kout,
                                                   float* __restrict__ Vout) {
    const int row = blockIdx.x;      // b*2048 + s
    const int b = row >> 11;
    const int s = row & 2047;
    const int t = threadIdx.x;
    const float* qrow = Qf + (size_t)row * 2048;
#pragma unroll
    for (int it = 0; it < 4; ++it) {
        int p = t + it * 256;        // pair index 0..1023
        int h = p >> 6;
        int i = p & 63;
        float fr  = exp2f(-(float)i * 0.20762050593045858f);  // 10000^(-i/64)
        float ang = (float)s * fr;
        float sn, c;
        sincosf(ang, &sn, &c);
        float x1 = qrow[h * 128 + i];
        float x2 = qrow[h * 128 + i + 64];
        size_t qb = (((size_t)(b * 16 + h)) * 2048 + s) * 128;
        Qb[qb + i]      = f2bf(x1 * c - x2 * sn);
        Qb[qb + i + 64] = f2bf(x2 * c + x1 * sn);
    }
    const float* kvrow = KVf + (size_t)row * 256;
    if (t < 128) {
        float kv = kvrow[t];
        float vv = kvrow[128 + t];
        Kout[(size_t)row * 128 + t] = kv;
        Vout[(size_t)row * 128 + t] = vv;
        Vt[((size_t)(b * 128 + t)) * 2048 + s] = f2bf(vv);
    }
    if (t < 64) {
        float fr  = exp2f(-(float)t * 0.20762050593045858f);
        float ang = (float)s * fr;
        float sn, c;
        sincosf(ang, &sn, &c);
        float x1 = kvrow[t];
        float x2 = kvrow[t + 64];
        size_t ko = ((size_t)b * 2048 + s) * 128;
        Kb[ko + t]      = f2bf(x1 * c - x2 * sn);
        Kb[ko + t + 64] = f2bf(x2 * c + x1 * sn);
    }
}

// ---------------- causal flash attention (MQA), block-cooperative LDS staging ----
// CHANGE vs passed round 5: K/V tiles staged into LDS via global_load_lds (async,
// zero VGPR cost), shared by all 4 waves; each wave owns one q-tile {4g+w}. LDS
// layouts XOR-swizzled (phys granule = logical granule ^ (row&15), self-inverse)
// with the inverse applied on the per-lane GLOBAL source address (rule #21).
// K tile: [64 rows][128 bf16] (16 granules/row). V tile: [64 dpair][2x64 keys]
// (16 granules/row, d = 2*row + parity). Waves 0,1 skip the block's last key-tile
// (barrier-only). Softmax/pack/epilogue verbatim from passed round 5.
__global__ __launch_bounds__(256, 2) void attn_k(const unsigned short* __restrict__ Qb,
                                                 const unsigned short* __restrict__ Kb,
                                                 const unsigned short* __restrict__ Vt,
                                                 unsigned short* __restrict__ Ob) {
    const int g = 15 - blockIdx.x;           // longest blocks dispatch first
    const int h = blockIdx.y, b = blockIdx.z;
    const int lane = threadIdx.x & 63;
    const int w = threadIdx.x >> 6;
    const int j = 4 * g + w;                 // this wave's q-tile (0..63)
    const int q0 = j * 32;
    const int lq = lane & 31;                // q row owned by this lane
    const int hl = lane >> 5;                // lane half
    const int kofs = hl * 8;                 // k-dim offset inside a 16-chunk
    const int my_nkt = 2 * g + 1 + (w >> 1); // key tiles for this wave's q-tile
    const int NKT = 2 * g + 2;               // block loop count

    __shared__ __align__(16) unsigned short Ks[8192];   // 16 KB
    __shared__ __align__(16) unsigned short Vs[8192];   // 16 KB

    const unsigned short* kbB = Kb + (size_t)b * 2048 * 128;
    const unsigned short* vtB = Vt + (size_t)b * 128 * 2048;
    const float csc = 0.12751782377892224f;  // (1/sqrt(128)) * log2(e)

    // --- staging invariants: wave w covers dest granules [w*256 + c*64 + lane] ---
    int k_r[4], k_gc[4], v_d[4], v_kg[4];
    unsigned short *kdst[4], *vdst[4];
#pragma unroll
    for (int c = 0; c < 4; ++c) {
        int G = w * 256 + c * 64 + lane;
        int r = G >> 4;
        int gc = (G & 15) ^ (r & 15);        // logical granule (self-inverse XOR)
        k_r[c] = r; k_gc[c] = gc;
        v_d[c] = r * 2 + (gc >> 3); v_kg[c] = gc & 7;
        kdst[c] = Ks + (w * 2048 + c * 512); // (w*256+c*64) granules * 8 elems
        vdst[c] = Vs + (w * 2048 + c * 512);
    }

    // --- Q fragment (held in regs) ---
    const unsigned short* qp = Qb + (((size_t)(b * 16 + h)) * 2048 + q0 + lq) * 128 + kofs;
    bf16x8 qf[8];
#pragma unroll
    for (int c = 0; c < 8; ++c)
        qf[c] = *reinterpret_cast<const bf16x8*>(qp + 16 * c);

    f32x16 O[4];
#pragma unroll
    for (int dt = 0; dt < 4; ++dt) O[dt] = zero16();
    float m = -1e30f, l = 0.f;

    for (int kt = 0; kt < NKT; ++kt) {
        // --- async stage K/V tile kt (all waves, 8 GLL16 calls each) ---
#pragma unroll
        for (int c = 0; c < 4; ++c) {
            GLL16(kbB + (size_t)(64 * kt + k_r[c]) * 128 + k_gc[c] * 8, kdst[c]);
            GLL16(vtB + (size_t)v_d[c] * 2048 + kt * 64 + v_kg[c] * 8, vdst[c]);
        }
        __syncthreads();   // drains vmcnt(0): LDS tile ready
        if (kt < my_nkt) {
            // --- K fragments from LDS (swizzled read) ---
            bf16x8 kf0[8], kf1[8];
            const int r0 = lq, r1 = lq + 32;
#pragma unroll
            for (int c = 0; c < 8; ++c) {
                kf0[c] = *reinterpret_cast<const bf16x8*>(
                    (const char*)Ks + r0 * 256 + (((2 * c + hl) ^ (r0 & 15)) * 16));
                kf1[c] = *reinterpret_cast<const bf16x8*>(
                    (const char*)Ks + r1 * 256 + (((2 * c + hl) ^ (r1 & 15)) * 16));
            }
            // --- S^T = K · Q^T ---
            f32x16 S0 = zero16(), S1 = zero16();
#pragma unroll
            for (int c = 0; c < 8; ++c) {
                S0 = __builtin_amdgcn_mfma_f32_32x32x16_bf16(kf0[c], qf[c], S0, 0, 0, 0);
                S1 = __builtin_amdgcn_mfma_f32_32x32x16_bf16(kf1[c], qf[c], S1, 0, 0, 0);
            }
            // --- softmax (verbatim round 5) ---
            float sc[32];
            const bool lastt = (kt == my_nkt - 1);
#pragma unroll
            for (int s = 0; s < 2; ++s)
#pragma unroll
                for (int r = 0; r < 16; ++r) {
                    float v = (s ? S1[r] : S0[r]) * csc;
                    if (lastt) {
                        int key = 64 * kt + 32 * s + (r & 3) + 8 * (r >> 2) + 4 * hl;
                        if (key > q0 + lq) v = -3.0e38f;
                    }
                    sc[16 * s + r] = v;
                }
            float tm[16];
#pragma unroll
            for (int i = 0; i < 16; ++i) tm[i] = fmaxf(sc[i], sc[i + 16]);
#pragma unroll
            for (int st = 8; st > 0; st >>= 1)
#pragma unroll
                for (int i = 0; i < st; ++i) tm[i] = fmaxf(tm[i], tm[i + st]);
            float mt = fmaxf(tm[0], __shfl_xor(tm[0], 32));
            float mn = fmaxf(m, mt);
            float corr = __builtin_amdgcn_exp2f(m - mn);
            m = mn;
#pragma unroll
            for (int i = 0; i < 32; ++i) sc[i] = __builtin_amdgcn_exp2f(sc[i] - mn);
            float ts[16];
#pragma unroll
            for (int i = 0; i < 16; ++i) ts[i] = sc[i] + sc[i + 16];
#pragma unroll
            for (int st = 8; st > 0; st >>= 1)
#pragma unroll
                for (int i = 0; i < st; ++i) ts[i] += ts[i + st];
            l = l * corr + ts[0] + __shfl_xor(ts[0], 32);
#pragma unroll
            for (int dt = 0; dt < 4; ++dt)
#pragma unroll
                for (int r = 0; r < 16; ++r) O[dt][r] *= corr;
            // --- pack P into PV B-fragments (verbatim round 5) ---
            unsigned pw[4][4];
#pragma unroll
            for (int s = 0; s < 2; ++s)
#pragma unroll
                for (int c2 = 0; c2 < 2; ++c2) {
                    const int rb = 16 * s + 8 * c2;
                    unsigned X0 = pk2(sc[rb + 0], sc[rb + 1]);
                    unsigned X1 = pk2(sc[rb + 2], sc[rb + 3]);
                    unsigned X2 = pk2(sc[rb + 4], sc[rb + 5]);
                    unsigned X3 = pk2(sc[rb + 6], sc[rb + 7]);
                    unsigned y0 = __shfl_xor(X0, 32);
                    unsigned y1 = __shfl_xor(X1, 32);
                    unsigned y2 = __shfl_xor(X2, 32);
                    unsigned y3 = __shfl_xor(X3, 32);
                    const int kc = 2 * s + c2;
                    pw[kc][0] = hl ? y2 : X0;
                    pw[kc][1] = hl ? y3 : X1;
                    pw[kc][2] = hl ? X2 : y0;
                    pw[kc][3] = hl ? X3 : y1;
                }
            // --- O^T += V^T · P^T, V fragments from LDS (swizzled read) ---
            const int vrow_lo = lq >> 1;     // (row & 15)
            const int vpar8 = (lq & 1) * 8;
#pragma unroll
            for (int kc = 0; kc < 4; ++kc) {
                uintv4 u;
                u.x = pw[kc][0]; u.y = pw[kc][1]; u.z = pw[kc][2]; u.w = pw[kc][3];
                bf16x8 pf = __builtin_bit_cast(bf16x8, u);
                const int gcl = vpar8 + 2 * kc + hl;
#pragma unroll
                for (int dt = 0; dt < 4; ++dt) {
                    const int vrow = 16 * dt + vrow_lo;
                    bf16x8 vf = *reinterpret_cast<const bf16x8*>(
                        (const char*)Vs + vrow * 256 + ((gcl ^ vrow_lo) * 16));
                    O[dt] = __builtin_amdgcn_mfma_f32_32x32x16_bf16(vf, pf, O[dt], 0, 0, 0);
                }
            }
        }
        __syncthreads();   // all reads done before next tile overwrites
    }

    // --- epilogue (verbatim round 4/5) ---
    float invl = 1.f / l;
    unsigned short* ob = Ob + ((size_t)(b * 2048 + q0 + lq)) * 2048 + h * 128;
#pragma unroll
    for (int dt = 0; dt < 4; ++dt)
#pragma unroll
        for (int gg = 0; gg < 4; ++gg) {
            ushortv4 ov;
            ov.x = f2bf(O[dt][4 * gg + 0] * invl);
            ov.y = f2bf(O[dt][4 * gg + 1] * invl);
            ov.z = f2bf(O[dt][4 * gg + 2] * invl);
            ov.w = f2bf(O[dt][4 * gg + 3] * invl);
            *reinterpret_cast<ushortv4*>(ob + 32 * dt + 8 * gg + 4 * hl) = ov;
        }
}

// ---------------- launch ----------------
extern "C" void kernel_launch(void* const* d_in, const int* in_sizes, int n_in,
                              void* d_out, int out_size, void* d_ws, size_t ws_size,
                              hipStream_t stream) {
    const float* x   = (const float*)d_in[0];
    const float* wq  = (const float*)d_in[1];
    const float* wkv = (const float*)d_in[2];
    const float* wo  = (const float*)d_in[3];

    float* out  = (float*)d_out;                 // (B,S,D) = 8388608
    float* Kout = out + 8388608;                 // (B,S,DH) = 524288
    float* Vout = Kout + 524288;

    char* ws = (char*)d_ws;
    unsigned short* xb   = (unsigned short*)(ws + 0);          // 16 MB
    unsigned short* wqb  = (unsigned short*)(ws + 16777216);   //  8 MB
    unsigned short* wkvT = (unsigned short*)(ws + 25165824);   //  1 MB
    unsigned short* wob  = (unsigned short*)(ws + 26214400);   //  8 MB
    float*          KVf  = (float*)(ws + 34603008);            //  4 MB
    float*          Qf   = (float*)(ws + 38797312);            // 32 MB
    unsigned short* Qb   = (unsigned short*)(ws + 0);          // 16 MB (aliases xb)
    unsigned short* Kb   = (unsigned short*)(ws + 16777216);   //  1 MB (aliases wqb)
    unsigned short* Vt   = (unsigned short*)(ws + 17825792);   //  1 MB (aliases wqb)
    unsigned short* Ob   = (unsigned short*)(ws + 34603008);   // 16 MB (aliases KVf/Qf)

    cast_bf16_k<<<8192, 256, 0, stream>>>(x,  xb,  2097152);
    cast_bf16_k<<<4096, 256, 0, stream>>>(wq, wqb, 1048576);
    cast_bf16_k<<<4096, 256, 0, stream>>>(wo, wob, 1048576);
    cast_t_wkv_k<<<2048, 256, 0, stream>>>(wkv, wkvT);

    gemm_bt<<<dim3(2, 32),  256, 0, stream>>>(xb, wkvT, KVf, 4096, 256,  2048);
    gemm_bt<<<dim3(16, 32), 256, 0, stream>>>(xb, wqb,  Qf,  4096, 2048, 2048);

    rope_pack_k<<<4096, 256, 0, stream>>>(Qf, KVf, Qb, Kb, Vt, Kout, Vout);

    attn_k<<<dim3(16, 16, 2), 256, 0, stream>>>(Qb, Kb, Vt, Ob);

    gemm_bt<<<dim3(16, 32), 256, 0, stream>>>(Ob, wob, out, 4096, 2048, 2048);
}

// Round 9
// 384.388 us; speedup vs baseline: 2.0430x; 1.0058x over previous
//
#include <hip/hip_runtime.h>
#include <hip/hip_bf16.h>
#include <cstdint>

// Problem constants: B=2, S=2048, D=2048, H=16, DH=128, past_length=0 (fixed).

typedef __attribute__((ext_vector_type(8))) __bf16 bf16x8;
typedef __attribute__((ext_vector_type(4))) float f32x4;
typedef __attribute__((ext_vector_type(16))) float f32x16;
typedef __attribute__((ext_vector_type(4))) float floatv4;
typedef __attribute__((ext_vector_type(4))) unsigned short ushortv4;
typedef __attribute__((ext_vector_type(4))) unsigned int uintv4;

__device__ __forceinline__ unsigned short f2bf(float f) {
    union { float f; unsigned u; } v; v.f = f;
    unsigned r = v.u + 0x7fffu + ((v.u >> 16) & 1u);
    return (unsigned short)(r >> 16);
}

__device__ __forceinline__ unsigned pk2(float a, float b) {
    return (unsigned)f2bf(a) | ((unsigned)f2bf(b) << 16);
}

__device__ __forceinline__ f32x16 zero16() {
    f32x16 z;
#pragma unroll
    for (int i = 0; i < 16; ++i) z[i] = 0.f;
    return z;
}

// global -> LDS async copy, 16B per lane. LDS dest = wave-uniform base + lane*16;
// global source is per-lane (enables swizzled staging via pre-swizzled source).
#define GLL16(g, l)                                                                   \
    __builtin_amdgcn_global_load_lds(                                                 \
        (const __attribute__((address_space(1))) void*)(uintptr_t)(g),                \
        (__attribute__((address_space(3))) void*)(unsigned)(uintptr_t)(l), 16, 0, 0)

// ---------------- cast kernels ----------------
__global__ __launch_bounds__(256) void cast_bf16_k(const float* __restrict__ src,
                                                   unsigned short* __restrict__ dst, int n4) {
    int i = blockIdx.x * 256 + threadIdx.x;
    if (i >= n4) return;
    floatv4 v = reinterpret_cast<const floatv4*>(src)[i];
    ushortv4 o;
    o.x = f2bf(v.x); o.y = f2bf(v.y); o.z = f2bf(v.z); o.w = f2bf(v.w);
    reinterpret_cast<ushortv4*>(dst)[i] = o;
}

// wkv (2048 x 256) f32 -> wkvT (256 x 2048) bf16
__global__ __launch_bounds__(256) void cast_t_wkv_k(const float* __restrict__ src,
                                                    unsigned short* __restrict__ dst) {
    int i = blockIdx.x * 256 + threadIdx.x;  // 0..524287
    int k = i >> 8, j = i & 255;
    dst[j * 2048 + k] = f2bf(src[i]);
}

// ---------------- BT GEMM: C[M][N] = A[M][K] * B[N][K]^T (bf16 in, f32 out) -------
__global__ __launch_bounds__(256) void gemm_bt(const unsigned short* __restrict__ A,
                                               const unsigned short* __restrict__ B,
                                               float* __restrict__ C,
                                               int M, int N, int K) {
    __shared__ __align__(16) unsigned short As[4096];  // [128][32]
    __shared__ __align__(16) unsigned short Bs[4096];
    const int tid  = threadIdx.x;
    const int lane = tid & 63;
    const int wid  = tid >> 6;
    const int wr   = wid >> 1;
    const int wc   = wid & 1;
    const size_t row0 = (size_t)blockIdx.y * 128;
    const size_t col0 = (size_t)blockIdx.x * 128;
    f32x4 acc[4][4];
#pragma unroll
    for (int m = 0; m < 4; ++m)
#pragma unroll
        for (int n = 0; n < 4; ++n) acc[m][n] = (f32x4){0.f, 0.f, 0.f, 0.f};

    const int srow = tid >> 2;
    const int scol = (tid & 3) << 3;
    const unsigned short* Ag = A + (row0 + srow) * (size_t)K + scol;
    const unsigned short* Bg = B + (col0 + srow) * (size_t)K + scol;
    unsigned short* AsW = &As[wid << 9];
    unsigned short* BsW = &Bs[wid << 9];

    const int lrow = lane & 15;
    const int lk   = (lane >> 4) << 3;

    for (int k0 = 0; k0 < K; k0 += 32) {
        GLL16(Ag + k0, AsW);
        GLL16(Ag + k0 + (size_t)64 * K, AsW + 2048);
        GLL16(Bg + k0, BsW);
        GLL16(Bg + k0 + (size_t)64 * K, BsW + 2048);
        __syncthreads();
        bf16x8 af[4], bfr[4];
#pragma unroll
        for (int m = 0; m < 4; ++m)
            af[m] = *reinterpret_cast<const bf16x8*>(&As[(wr * 64 + m * 16 + lrow) * 32 + lk]);
#pragma unroll
        for (int n = 0; n < 4; ++n)
            bfr[n] = *reinterpret_cast<const bf16x8*>(&Bs[(wc * 64 + n * 16 + lrow) * 32 + lk]);
#pragma unroll
        for (int m = 0; m < 4; ++m)
#pragma unroll
            for (int n = 0; n < 4; ++n)
                acc[m][n] = __builtin_amdgcn_mfma_f32_16x16x32_bf16(af[m], bfr[n], acc[m][n], 0, 0, 0);
        __syncthreads();
    }
    const size_t orow0 = row0 + wr * 64 + ((lane >> 4) << 2);
    const size_t ocol  = col0 + wc * 64 + lrow;
#pragma unroll
    for (int m = 0; m < 4; ++m)
#pragma unroll
        for (int n = 0; n < 4; ++n)
#pragma unroll
            for (int r = 0; r < 4; ++r)
                C[(orow0 + m * 16 + r) * (size_t)N + ocol + n * 16] = acc[m][n][r];
}

// ---------------- RoPE + pack (unchanged, passed rounds 4/5/7) ----------------
__global__ __launch_bounds__(256) void rope_pack_k(const float* __restrict__ Qf,
                                                   const float* __restrict__ KVf,
                                                   unsigned short* __restrict__ Qb,
                                                   unsigned short* __restrict__ Kb,
                                                   unsigned short* __restrict__ Vt,
                                                   float* __restrict__ Kout,
                                                   float* __restrict__ Vout) {
    const int row = blockIdx.x;      // b*2048 + s
    const int b = row >> 11;
    const int s = row & 2047;
    const int t = threadIdx.x;
    const float* qrow = Qf + (size_t)row * 2048;
#pragma unroll
    for (int it = 0; it < 4; ++it) {
        int p = t + it * 256;        // pair index 0..1023
        int h = p >> 6;
        int i = p & 63;
        float fr  = exp2f(-(float)i * 0.20762050593045858f);  // 10000^(-i/64)
        float ang = (float)s * fr;
        float sn, c;
        sincosf(ang, &sn, &c);
        float x1 = qrow[h * 128 + i];
        float x2 = qrow[h * 128 + i + 64];
        size_t qb = (((size_t)(b * 16 + h)) * 2048 + s) * 128;
        Qb[qb + i]      = f2bf(x1 * c - x2 * sn);
        Qb[qb + i + 64] = f2bf(x2 * c + x1 * sn);
    }
    const float* kvrow = KVf + (size_t)row * 256;
    if (t < 128) {
        float kv = kvrow[t];
        float vv = kvrow[128 + t];
        Kout[(size_t)row * 128 + t] = kv;
        Vout[(size_t)row * 128 + t] = vv;
        Vt[((size_t)(b * 128 + t)) * 2048 + s] = f2bf(vv);
    }
    if (t < 64) {
        float fr  = exp2f(-(float)t * 0.20762050593045858f);
        float ang = (float)s * fr;
        float sn, c;
        sincosf(ang, &sn, &c);
        float x1 = kvrow[t];
        float x2 = kvrow[t + 64];
        size_t ko = ((size_t)b * 2048 + s) * 128;
        Kb[ko + t]      = f2bf(x1 * c - x2 * sn);
        Kb[ko + t + 64] = f2bf(x2 * c + x1 * sn);
    }
}

// ---------------- causal flash attention (MQA), LDS staging + 2-phase prefetch ---
// CHANGE vs passed round 7: K/V LDS tiles double-buffered (T3 minimal 2-phase).
// Per iteration: issue STAGE(kt+1) into buf^1 FIRST, compute tile kt from buf,
// then one __syncthreads (vmcnt(0) drain lands after compute covers the load
// latency). Swizzle/softmax/pack/epilogue byte-identical to round 7.
__global__ __launch_bounds__(256, 2) void attn_k(const unsigned short* __restrict__ Qb,
                                                 const unsigned short* __restrict__ Kb,
                                                 const unsigned short* __restrict__ Vt,
                                                 unsigned short* __restrict__ Ob) {
    const int g = 15 - blockIdx.x;           // longest blocks dispatch first
    const int h = blockIdx.y, b = blockIdx.z;
    const int lane = threadIdx.x & 63;
    const int w = threadIdx.x >> 6;
    const int j = 4 * g + w;                 // this wave's q-tile (0..63)
    const int q0 = j * 32;
    const int lq = lane & 31;                // q row owned by this lane
    const int hl = lane >> 5;                // lane half
    const int kofs = hl * 8;                 // k-dim offset inside a 16-chunk
    const int my_nkt = 2 * g + 1 + (w >> 1); // key tiles for this wave's q-tile
    const int NKT = 2 * g + 2;               // block loop count

    __shared__ __align__(16) unsigned short Ks[2][8192];   // 32 KB (double-buffered)
    __shared__ __align__(16) unsigned short Vs[2][8192];   // 32 KB

    const unsigned short* kbB = Kb + (size_t)b * 2048 * 128;
    const unsigned short* vtB = Vt + (size_t)b * 128 * 2048;
    const float csc = 0.12751782377892224f;  // (1/sqrt(128)) * log2(e)

    // --- staging invariants: wave w covers dest granules [w*256 + c*64 + lane] ---
    int k_r[4], k_gc[4], v_d[4], v_kg[4];
#pragma unroll
    for (int c = 0; c < 4; ++c) {
        int G = w * 256 + c * 64 + lane;
        int r = G >> 4;
        int gc = (G & 15) ^ (r & 15);        // logical granule (self-inverse XOR)
        k_r[c] = r; k_gc[c] = gc;
        v_d[c] = r * 2 + (gc >> 3); v_kg[c] = gc & 7;
    }
    const int dstoff = w * 2048;             // wave dest base (elems) within a buffer

    // --- Q fragment (held in regs) ---
    const unsigned short* qp = Qb + (((size_t)(b * 16 + h)) * 2048 + q0 + lq) * 128 + kofs;
    bf16x8 qf[8];
#pragma unroll
    for (int c = 0; c < 8; ++c)
        qf[c] = *reinterpret_cast<const bf16x8*>(qp + 16 * c);

    f32x16 O[4];
#pragma unroll
    for (int dt = 0; dt < 4; ++dt) O[dt] = zero16();
    float m = -1e30f, l = 0.f;

    // --- prologue: stage tile 0 into buffer 0 ---
#pragma unroll
    for (int c = 0; c < 4; ++c) {
        GLL16(kbB + (size_t)k_r[c] * 128 + k_gc[c] * 8, &Ks[0][dstoff + c * 512]);
        GLL16(vtB + (size_t)v_d[c] * 2048 + v_kg[c] * 8, &Vs[0][dstoff + c * 512]);
    }
    __syncthreads();   // tile 0 ready

    int cur = 0;
    for (int kt = 0; kt < NKT; ++kt) {
        // --- prefetch tile kt+1 into the other buffer (async, no wait) ---
        if (kt + 1 < NKT) {
            const int nxt = cur ^ 1;
#pragma unroll
            for (int c = 0; c < 4; ++c) {
                GLL16(kbB + (size_t)(64 * (kt + 1) + k_r[c]) * 128 + k_gc[c] * 8,
                      &Ks[nxt][dstoff + c * 512]);
                GLL16(vtB + (size_t)v_d[c] * 2048 + (kt + 1) * 64 + v_kg[c] * 8,
                      &Vs[nxt][dstoff + c * 512]);
            }
        }
        if (kt < my_nkt) {
            // --- K fragments from LDS (swizzled read) ---
            bf16x8 kf0[8], kf1[8];
            const int r0 = lq, r1 = lq + 32;
#pragma unroll
            for (int c = 0; c < 8; ++c) {
                kf0[c] = *reinterpret_cast<const bf16x8*>(
                    (const char*)&Ks[cur][0] + r0 * 256 + (((2 * c + hl) ^ (r0 & 15)) * 16));
                kf1[c] = *reinterpret_cast<const bf16x8*>(
                    (const char*)&Ks[cur][0] + r1 * 256 + (((2 * c + hl) ^ (r1 & 15)) * 16));
            }
            // --- S^T = K · Q^T ---
            f32x16 S0 = zero16(), S1 = zero16();
#pragma unroll
            for (int c = 0; c < 8; ++c) {
                S0 = __builtin_amdgcn_mfma_f32_32x32x16_bf16(kf0[c], qf[c], S0, 0, 0, 0);
                S1 = __builtin_amdgcn_mfma_f32_32x32x16_bf16(kf1[c], qf[c], S1, 0, 0, 0);
            }
            // --- softmax (verbatim) ---
            float sc[32];
            const bool lastt = (kt == my_nkt - 1);
#pragma unroll
            for (int s = 0; s < 2; ++s)
#pragma unroll
                for (int r = 0; r < 16; ++r) {
                    float v = (s ? S1[r] : S0[r]) * csc;
                    if (lastt) {
                        int key = 64 * kt + 32 * s + (r & 3) + 8 * (r >> 2) + 4 * hl;
                        if (key > q0 + lq) v = -3.0e38f;
                    }
                    sc[16 * s + r] = v;
                }
            float tm[16];
#pragma unroll
            for (int i = 0; i < 16; ++i) tm[i] = fmaxf(sc[i], sc[i + 16]);
#pragma unroll
            for (int st = 8; st > 0; st >>= 1)
#pragma unroll
                for (int i = 0; i < st; ++i) tm[i] = fmaxf(tm[i], tm[i + st]);
            float mt = fmaxf(tm[0], __shfl_xor(tm[0], 32));
            float mn = fmaxf(m, mt);
            float corr = __builtin_amdgcn_exp2f(m - mn);
            m = mn;
#pragma unroll
            for (int i = 0; i < 32; ++i) sc[i] = __builtin_amdgcn_exp2f(sc[i] - mn);
            float ts[16];
#pragma unroll
            for (int i = 0; i < 16; ++i) ts[i] = sc[i] + sc[i + 16];
#pragma unroll
            for (int st = 8; st > 0; st >>= 1)
#pragma unroll
                for (int i = 0; i < st; ++i) ts[i] += ts[i + st];
            l = l * corr + ts[0] + __shfl_xor(ts[0], 32);
#pragma unroll
            for (int dt = 0; dt < 4; ++dt)
#pragma unroll
                for (int r = 0; r < 16; ++r) O[dt][r] *= corr;
            // --- pack P into PV B-fragments (verbatim) ---
            unsigned pw[4][4];
#pragma unroll
            for (int s = 0; s < 2; ++s)
#pragma unroll
                for (int c2 = 0; c2 < 2; ++c2) {
                    const int rb = 16 * s + 8 * c2;
                    unsigned X0 = pk2(sc[rb + 0], sc[rb + 1]);
                    unsigned X1 = pk2(sc[rb + 2], sc[rb + 3]);
                    unsigned X2 = pk2(sc[rb + 4], sc[rb + 5]);
                    unsigned X3 = pk2(sc[rb + 6], sc[rb + 7]);
                    unsigned y0 = __shfl_xor(X0, 32);
                    unsigned y1 = __shfl_xor(X1, 32);
                    unsigned y2 = __shfl_xor(X2, 32);
                    unsigned y3 = __shfl_xor(X3, 32);
                    const int kc = 2 * s + c2;
                    pw[kc][0] = hl ? y2 : X0;
                    pw[kc][1] = hl ? y3 : X1;
                    pw[kc][2] = hl ? X2 : y0;
                    pw[kc][3] = hl ? X3 : y1;
                }
            // --- O^T += V^T · P^T, V fragments from LDS (swizzled read) ---
            const int vrow_lo = lq >> 1;     // (row & 15)
            const int vpar8 = (lq & 1) * 8;
#pragma unroll
            for (int kc = 0; kc < 4; ++kc) {
                uintv4 u;
                u.x = pw[kc][0]; u.y = pw[kc][1]; u.z = pw[kc][2]; u.w = pw[kc][3];
                bf16x8 pf = __builtin_bit_cast(bf16x8, u);
                const int gcl = vpar8 + 2 * kc + hl;
#pragma unroll
                for (int dt = 0; dt < 4; ++dt) {
                    const int vrow = 16 * dt + vrow_lo;
                    bf16x8 vf = *reinterpret_cast<const bf16x8*>(
                        (const char*)&Vs[cur][0] + vrow * 256 + ((gcl ^ vrow_lo) * 16));
                    O[dt] = __builtin_amdgcn_mfma_f32_32x32x16_bf16(vf, pf, O[dt], 0, 0, 0);
                }
            }
        }
        __syncthreads();   // drains prefetch vmcnt + guards buffer reuse
        cur ^= 1;
    }

    // --- epilogue (verbatim) ---
    float invl = 1.f / l;
    unsigned short* ob = Ob + ((size_t)(b * 2048 + q0 + lq)) * 2048 + h * 128;
#pragma unroll
    for (int dt = 0; dt < 4; ++dt)
#pragma unroll
        for (int gg = 0; gg < 4; ++gg) {
            ushortv4 ov;
            ov.x = f2bf(O[dt][4 * gg + 0] * invl);
            ov.y = f2bf(O[dt][4 * gg + 1] * invl);
            ov.z = f2bf(O[dt][4 * gg + 2] * invl);
            ov.w = f2bf(O[dt][4 * gg + 3] * invl);
            *reinterpret_cast<ushortv4*>(ob + 32 * dt + 8 * gg + 4 * hl) = ov;
        }
}

// ---------------- launch ----------------
extern "C" void kernel_launch(void* const* d_in, const int* in_sizes, int n_in,
                              void* d_out, int out_size, void* d_ws, size_t ws_size,
                              hipStream_t stream) {
    const float* x   = (const float*)d_in[0];
    const float* wq  = (const float*)d_in[1];
    const float* wkv = (const float*)d_in[2];
    const float* wo  = (const float*)d_in[3];

    float* out  = (float*)d_out;                 // (B,S,D) = 8388608
    float* Kout = out + 8388608;                 // (B,S,DH) = 524288
    float* Vout = Kout + 524288;

    char* ws = (char*)d_ws;
    unsigned short* xb   = (unsigned short*)(ws + 0);          // 16 MB
    unsigned short* wqb  = (unsigned short*)(ws + 16777216);   //  8 MB
    unsigned short* wkvT = (unsigned short*)(ws + 25165824);   //  1 MB
    unsigned short* wob  = (unsigned short*)(ws + 26214400);   //  8 MB
    float*          KVf  = (float*)(ws + 34603008);            //  4 MB
    float*          Qf   = (float*)(ws + 38797312);            // 32 MB
    unsigned short* Qb   = (unsigned short*)(ws + 0);          // 16 MB (aliases xb)
    unsigned short* Kb   = (unsigned short*)(ws + 16777216);   //  1 MB (aliases wqb)
    unsigned short* Vt   = (unsigned short*)(ws + 17825792);   //  1 MB (aliases wqb)
    unsigned short* Ob   = (unsigned short*)(ws + 34603008);   // 16 MB (aliases KVf/Qf)

    cast_bf16_k<<<8192, 256, 0, stream>>>(x,  xb,  2097152);
    cast_bf16_k<<<4096, 256, 0, stream>>>(wq, wqb, 1048576);
    cast_bf16_k<<<4096, 256, 0, stream>>>(wo, wob, 1048576);
    cast_t_wkv_k<<<2048, 256, 0, stream>>>(wkv, wkvT);

    gemm_bt<<<dim3(2, 32),  256, 0, stream>>>(xb, wkvT, KVf, 4096, 256,  2048);
    gemm_bt<<<dim3(16, 32), 256, 0, stream>>>(xb, wqb,  Qf,  4096, 2048, 2048);

    rope_pack_k<<<4096, 256, 0, stream>>>(Qf, KVf, Qb, Kb, Vt, Kout, Vout);

    attn_k<<<dim3(16, 16, 2), 256, 0, stream>>>(Qb, Kb, Vt, Ob);

    gemm_bt<<<dim3(16, 32), 256, 0, stream>>>(Ob, wob, out, 4096, 2048, 2048);
}